// Round 7
// baseline (458.417 us; speedup 1.0000x reference)
//
#include <hip/hip_runtime.h>

// S4 (SSSD) layer: L=2048, B=16, H=256, N2=32.
// R7: OUTPUT IS FLOAT32 (jax-default f32 reference; "bf16" in the test label
// is a hardcoded string). Six rounds failed because k6 packed bf16 u16 into a
// float* buffer. Pipeline (verified by R5 liveness + R6 on-device FFT-vs-
// direct-conv differential): k1 kergen(f64) -> k2a ifft2048 -> k2b fft4096 ->
// k3 transpose -> k4 FFT conv + D-skip + GELU -> k5 GEMM+GLU -> k6 LN (f32).

#define PI_F 3.14159265358979323846f
#define PI_D 3.14159265358979323846

// ---------------- complex helpers ----------------
struct cd { double x, y; };
__device__ __forceinline__ cd cmuld(cd a, cd b) {
    return cd{a.x*b.x - a.y*b.y, a.x*b.y + a.y*b.x};
}
__device__ __forceinline__ cd cdivd(cd a, cd b) {
    double inv = 1.0 / (b.x*b.x + b.y*b.y);
    return cd{(a.x*b.x + a.y*b.y) * inv, (a.y*b.x - a.x*b.y) * inv};
}
__device__ __forceinline__ cd caccum(cd r, cd v, cd i1, cd i2) {
    r.x += v.x*i1.x - v.y*i1.y + v.x*i2.x + v.y*i2.y;
    r.y += v.x*i1.y + v.y*i1.x + v.x*i2.y - v.y*i2.x;
    return r;
}
__device__ __forceinline__ float2 cmulf(float2 a, float2 b) {
    return make_float2(a.x*b.x - a.y*b.y, a.x*b.y + a.y*b.x);
}

// ---------------- in-place radix-2 DIT FFT in LDS ----------------
__device__ __forceinline__ void fft_dit(float2* A, int N, int logN, float sign,
                                        int tid, int nthr) {
    __syncthreads();
    for (int j = tid; j < N; j += nthr) {
        int r = (int)(__brev((unsigned)j) >> (32 - logN));
        if (r > j) { float2 t = A[j]; A[j] = A[r]; A[r] = t; }
    }
    __syncthreads();
    const int half = N >> 1;
    for (int s = 0; s < logN; ++s) {
        const int Ns = 1 << s;
        for (int j = tid; j < half; j += nthr) {
            int k  = j & (Ns - 1);
            int i0 = ((j >> s) << (s + 1)) | k;
            int i1 = i0 + Ns;
            float ang = sign * PI_F * (float)k / (float)Ns;
            float sn, cs;
            __sincosf(ang, &sn, &cs);
            float2 a = A[i0], b = A[i1];
            float2 t = make_float2(cs*b.x - sn*b.y, cs*b.y + sn*b.x);
            A[i0] = make_float2(a.x + t.x, a.y + t.y);
            A[i1] = make_float2(a.x - t.x, a.y - t.y);
        }
        __syncthreads();
    }
}

// ---------------- K1: NPLR kernel generation (f64) ----------------
__global__ void k1_kergen(const float* __restrict__ log_dt, const float* __restrict__ wlr,
                          const float* __restrict__ wim, const float* __restrict__ Pre,
                          const float* __restrict__ Pim, const float* __restrict__ Bre,
                          const float* __restrict__ Bim, const float* __restrict__ Cre,
                          const float* __restrict__ Cim, float2* __restrict__ kf_out)
{
    int h = blockIdx.x;
    int f = blockIdx.y * 256 + threadIdx.x;
    if (f > 1024) return;
    double dt = exp((double)log_dt[h]);
    double th = -2.0 * PI_D * (double)f / 2048.0;
    double ox = cos(th), oy = sin(th);
    cd onep{1.0 + ox, oy};
    cd z = cdivd(cd{2.0*(1.0 - ox), -2.0*oy}, onep);
    cd r00{0,0}, r01{0,0}, r02{0,0}, r10{0,0}, r11{0,0}, r12{0,0};
    const int base = h * 32;
    for (int n = 0; n < 32; ++n) {
        double wre = -exp((double)wlr[base+n]) * dt;
        double wi  = (double)wim[base+n] * dt;
        cd i1 = cdivd(cd{1.0, 0.0}, cd{z.x - wre, z.y - wi});
        cd i2 = cdivd(cd{1.0, 0.0}, cd{z.x - wre, z.y + wi});
        cd B0{(double)Bre[base+n], (double)Bim[base+n]};
        cd P0{(double)Pre[base+n], (double)Pim[base+n]};
        cd C0{(double)Cre[base+n], (double)Cim[base+n]};
        cd C1{(double)Cre[8192+base+n], (double)Cim[8192+base+n]};
        cd C2{P0.x, -P0.y};
        r00 = caccum(r00, cmuld(B0, C0), i1, i2);
        r01 = caccum(r01, cmuld(B0, C1), i1, i2);
        r02 = caccum(r02, cmuld(B0, C2), i1, i2);
        r10 = caccum(r10, cmuld(P0, C0), i1, i2);
        r11 = caccum(r11, cmuld(P0, C1), i1, i2);
        r12 = caccum(r12, cmuld(P0, C2), i1, i2);
    }
    r00.x *= dt; r00.y *= dt; r01.x *= dt; r01.y *= dt; r02.x *= dt; r02.y *= dt;
    r10.x *= dt; r10.y *= dt; r11.x *= dt; r11.y *= dt; r12.x *= dt; r12.y *= dt;
    cd den{1.0 + r12.x, r12.y};
    cd fac = cdivd(cd{2.0, 0.0}, onep);
    cd t0 = cdivd(cmuld(r02, r10), den);
    cd k0{r00.x - t0.x, r00.y - t0.y};
    k0 = cmuld(k0, fac);
    cd t1 = cdivd(cmuld(r02, r11), den);
    cd k1{r01.x - t1.x, r01.y - t1.y};
    k1 = cmuld(k1, fac);
    kf_out[(size_t)h * 1025 + f]         = make_float2((float)k0.x, (float)k0.y);
    kf_out[(size_t)(256 + h) * 1025 + f] = make_float2((float)k1.x, (float)k1.y);
}

// ---------------- K2a: hermitian-extend + ifft2048 -> time kernel -----------
__global__ __launch_bounds__(256) void k2a_ifft(const float2* __restrict__ kfin,
                                                float* __restrict__ kt)
{
    __shared__ float2 A[2048];
    int r = blockIdx.x, tid = threadIdx.x;
    const float2* src = kfin + (size_t)r * 1025;
    for (int j = tid; j < 2048; j += 256) {
        float2 q;
        if (j == 0)          { q = src[0];    q.y = 0.0f; }
        else if (j < 1024)   { q = src[j]; }
        else if (j == 1024)  { q = src[1024]; q.y = 0.0f; }
        else { float2 t = src[2048 - j]; q = make_float2(t.x, -t.y); }
        A[j] = q;
    }
    fft_dit(A, 2048, 11, +1.0f, tid, 256);
    const float scl = 1.0f / 2048.0f;
    for (int j = tid; j < 2048; j += 256)
        kt[(size_t)r * 2048 + j] = A[j].x * scl;
}

// ---------------- K2b: kk = [k0, rev(k1)] -> fft4096 -> kf ------------------
__global__ __launch_bounds__(256) void k2b_fft(const float* __restrict__ kt,
                                               float2* __restrict__ kfout)
{
    __shared__ float2 A[4096];
    int h = blockIdx.x, tid = threadIdx.x;
    const float* k0 = kt + (size_t)h * 2048;
    const float* k1 = kt + (size_t)(256 + h) * 2048;
    for (int j = tid; j < 2048; j += 256) {
        A[j]        = make_float2(k0[j], 0.0f);
        A[2048 + j] = make_float2(k1[2047 - j], 0.0f);
    }
    fft_dit(A, 4096, 12, -1.0f, tid, 256);
    for (int F = tid; F <= 2048; F += 256)
        kfout[(size_t)h * 2049 + F] = A[F];
}

// ---------------- K3: transpose x (2048 x 4096) -> u (4096 x 2048) ----------
__global__ void k3_transpose(const float* __restrict__ x, float* __restrict__ u)
{
    __shared__ float tile[32][33];
    int p0 = blockIdx.x * 32;
    int l0 = blockIdx.y * 32;
    int tx = threadIdx.x, ty = threadIdx.y;
    for (int i = ty; i < 32; i += 8)
        tile[i][tx] = x[(size_t)(l0 + i) * 4096 + p0 + tx];
    __syncthreads();
    for (int i = ty; i < 32; i += 8)
        u[(size_t)(p0 + i) * 2048 + l0 + tx] = tile[tx][i];
}

// ---------------- K4: per-(b,h) in-place FFT conv + D-skip + GELU -----------
__global__ __launch_bounds__(256) void k4_conv(const float* __restrict__ u,
        const float2* __restrict__ kf, const float* __restrict__ Dp, float* __restrict__ yg)
{
    __shared__ float2 A[4096];
    int h = blockIdx.x & 255;
    int b = blockIdx.x >> 8;
    int tid = threadIdx.x;
    const float* ur = u + (size_t)(b * 256 + h) * 2048;
    for (int j = tid; j < 2048; j += 256) {
        A[j]        = make_float2(ur[j], 0.0f);
        A[2048 + j] = make_float2(0.0f, 0.0f);
    }
    fft_dit(A, 4096, 12, -1.0f, tid, 256);
    const float2* kfh = kf + (size_t)h * 2049;
    for (int f = tid; f < 4096; f += 256) {
        float2 K;
        if (f <= 2048) K = kfh[f];
        else { float2 t = kfh[4096 - f]; K = make_float2(t.x, -t.y); }
        A[f] = cmulf(A[f], K);
    }
    fft_dit(A, 4096, 12, +1.0f, tid, 256);
    float d = Dp[h];
    float* o = yg + (size_t)(b * 256 + h) * 2048;
    const float iscl = 1.0f / 4096.0f;
    for (int j = tid; j < 2048; j += 256) {
        float y = A[j].x * iscl + d * ur[j];
        o[j] = 0.5f * y * (1.0f + erff(y * 0.70710678118654752f));
    }
}

// ---------------- K5: y2 = Wout@yg + bout ; GLU ; in-place ------------------
__global__ __launch_bounds__(256) void k5_gemm_glu(float* __restrict__ yg,
        const float* __restrict__ W, const float* __restrict__ bout)
{
    __shared__ float yt[256 * 32];
    int b  = blockIdx.y;
    int l0 = blockIdx.x * 32;
    int tid = threadIdx.x;
    for (int idx = tid; idx < 256 * 32; idx += 256) {
        int hh = idx >> 5, l = idx & 31;
        yt[idx] = yg[(size_t)(b * 256 + hh) * 2048 + l0 + l];
    }
    __syncthreads();
    float accA[32], accB[32];
    #pragma unroll
    for (int l = 0; l < 32; ++l) { accA[l] = 0.0f; accB[l] = 0.0f; }
    const float* wa_p = W + (size_t)tid * 256;
    const float* wb_p = W + (size_t)(256 + tid) * 256;
    #pragma unroll 4
    for (int hh = 0; hh < 256; ++hh) {
        float wa = wa_p[hh], wb = wb_p[hh];
        #pragma unroll
        for (int l = 0; l < 32; ++l) {
            float yv = yt[hh * 32 + l];
            accA[l] += wa * yv;
            accB[l] += wb * yv;
        }
    }
    float ba = bout[tid], bb = bout[256 + tid];
    float* o = yg + (size_t)(b * 256 + tid) * 2048 + l0;
    #pragma unroll
    for (int l = 0; l < 32; ++l) {
        float gate = accB[l] + bb;
        o[l] = (accA[l] + ba) / (1.0f + expf(-gate));
    }
}

// ---------------- K6: residual + LayerNorm + transpose-out (FLOAT32) --------
__global__ __launch_bounds__(256) void k6_ln(const float* __restrict__ g, const float* __restrict__ u,
        const float* __restrict__ gamma, const float* __restrict__ beta,
        float* __restrict__ out)
{
    __shared__ float redS[4][64], redQ[4][64], gam[256], bet[256];
    int b  = blockIdx.y;
    int l0 = blockIdx.x * 64;
    int tid = threadIdx.x;
    int l = tid & 63, hq = tid >> 6;
    gam[tid] = gamma[tid]; bet[tid] = beta[tid];
    float v[64];
    float s = 0.0f, q2 = 0.0f;
    const float* gp = g + (size_t)(b * 256 + hq * 64) * 2048 + l0 + l;
    const float* up = u + (size_t)(b * 256 + hq * 64) * 2048 + l0 + l;
    #pragma unroll
    for (int hh = 0; hh < 64; ++hh) {
        float val = gp[(size_t)hh * 2048] + up[(size_t)hh * 2048];
        v[hh] = val; s += val; q2 += val * val;
    }
    redS[hq][l] = s; redQ[hq][l] = q2;
    __syncthreads();
    float st = redS[0][l] + redS[1][l] + redS[2][l] + redS[3][l];
    float qt = redQ[0][l] + redQ[1][l] + redQ[2][l] + redQ[3][l];
    float mu = st * (1.0f / 256.0f);
    float var = qt * (1.0f / 256.0f) - mu * mu;
    float rstd = rsqrtf(var + 1e-5f);
    float* ob = out + (size_t)((l0 + l) * 16 + b) * 256 + hq * 64;
    #pragma unroll
    for (int o4 = 0; o4 < 16; ++o4) {
        float4 pk;
        int h0 = o4 * 4;
        pk.x = (v[h0+0] - mu) * rstd * gam[hq*64 + h0+0] + bet[hq*64 + h0+0];
        pk.y = (v[h0+1] - mu) * rstd * gam[hq*64 + h0+1] + bet[hq*64 + h0+1];
        pk.z = (v[h0+2] - mu) * rstd * gam[hq*64 + h0+2] + bet[hq*64 + h0+2];
        pk.w = (v[h0+3] - mu) * rstd * gam[hq*64 + h0+3] + bet[hq*64 + h0+3];
        *(float4*)(ob + h0) = pk;
    }
}

// ---------------- launch ----------------
extern "C" void kernel_launch(void* const* d_in, const int* in_sizes, int n_in,
                              void* d_out, int out_size, void* d_ws, size_t ws_size,
                              hipStream_t stream)
{
    (void)in_sizes; (void)n_in; (void)out_size; (void)ws_size;
    const float* x      = (const float*)d_in[0];
    const float* log_dt = (const float*)d_in[1];
    const float* wlr    = (const float*)d_in[2];
    const float* wim    = (const float*)d_in[3];
    const float* Pre    = (const float*)d_in[4];
    const float* Pim    = (const float*)d_in[5];
    const float* Bre    = (const float*)d_in[6];
    const float* Bim    = (const float*)d_in[7];
    const float* Cre    = (const float*)d_in[8];
    const float* Cim    = (const float*)d_in[9];
    const float* Dp     = (const float*)d_in[10];
    const float* Wout   = (const float*)d_in[11];
    const float* bout   = (const float*)d_in[12];
    const float* gamma  = (const float*)d_in[13];
    const float* beta   = (const float*)d_in[14];

    // ws: 64MB (u, yg). Scratch in d_out (33.5MB f32): kF 4.2MB + kfo 4.2MB +
    // kt 4.2MB = 12.6MB, dead before k6 overwrites the full output.
    float* ws  = (float*)d_ws;
    float* u   = ws;                 // 8,388,608 f = 32MB (B,H,L)
    float* yg  = ws + 8388608;       // 8,388,608 f = 32MB (B,H,L)
    char*  ob  = (char*)d_out;       // 33,554,432 B
    float2* kF  = (float2*)(ob);               // 4,198,400 B
    float2* kfo = (float2*)(ob + 4198400);     // 4,196,352 B
    float*  kt  = (float*) (ob + 8394752);     // 4,194,304 B (ends 12.6MB)

    k1_kergen<<<dim3(256, 5), 256, 0, stream>>>(log_dt, wlr, wim, Pre, Pim, Bre, Bim, Cre, Cim, kF);
    k2a_ifft<<<dim3(512), 256, 0, stream>>>(kF, kt);
    k2b_fft<<<dim3(256), 256, 0, stream>>>(kt, kfo);
    k3_transpose<<<dim3(128, 64), dim3(32, 8), 0, stream>>>(x, u);
    k4_conv<<<dim3(4096), 256, 0, stream>>>(u, kfo, Dp, yg);
    k5_gemm_glu<<<dim3(64, 16), 256, 0, stream>>>(yg, Wout, bout);
    k6_ln<<<dim3(32, 16), 256, 0, stream>>>(yg, u, gamma, beta, (float*)d_out);
}

// Round 8
// 317.519 us; speedup vs baseline: 1.4437x; 1.4437x over previous
//
#include <hip/hip_runtime.h>

// S4 (SSSD) layer: L=2048, B=16, H=256, N2=32. Output f32.
// R8 (first perf round): pair-packed FFTs (2 real signals per complex FFT),
// fused double-stage radix-2 DIT with LDS padding (kills 4.3e7 bank-conflict
// cycles), k2a+k2b fused into one kernel, register-tiled k5 GEMM (8 rows x
// 16 cols per thread, W pre-transposed), k6 coalesced store via LDS transpose.

#define PI_F 3.14159265358979323846f
#define PI_D 3.14159265358979323846
#define LP(i) ((i) + ((i) >> 4))    // LDS pad: +1 slot per 16 elements

// ---------------- complex helpers ----------------
struct cd { double x, y; };
__device__ __forceinline__ cd cmuld(cd a, cd b) {
    return cd{a.x*b.x - a.y*b.y, a.x*b.y + a.y*b.x};
}
__device__ __forceinline__ cd cdivd(cd a, cd b) {
    double inv = 1.0 / (b.x*b.x + b.y*b.y);
    return cd{(a.x*b.x + a.y*b.y) * inv, (a.y*b.x - a.x*b.y) * inv};
}
__device__ __forceinline__ cd caccum(cd r, cd v, cd i1, cd i2) {
    r.x += v.x*i1.x - v.y*i1.y + v.x*i2.x + v.y*i2.y;
    r.y += v.x*i1.y + v.y*i1.x + v.x*i2.y - v.y*i2.x;
    return r;
}
__device__ __forceinline__ float2 cmulf(float2 a, float2 b) {
    return make_float2(a.x*b.x - a.y*b.y, a.x*b.y + a.y*b.x);
}

// -------- in-place DIT FFT, fused double-stages, padded LDS addressing ------
// SGN=-1 forward (numpy), SGN=+1 inverse (unscaled). Hand-verified at N=4.
template<int SGN>
__device__ __forceinline__ void fft_fused(float2* A, int N, int logN,
                                          int tid, int nthr) {
    __syncthreads();
    for (int j = tid; j < N; j += nthr) {
        int r = (int)(__brev((unsigned)j) >> (32 - logN));
        if (r > j) { float2 t = A[LP(j)]; A[LP(j)] = A[LP(r)]; A[LP(r)] = t; }
    }
    __syncthreads();
    int s = 0;
    if (logN & 1) {               // single radix-2 stage (s=0, twiddle = 1)
        for (int j = tid; j < (N >> 1); j += nthr) {
            int i0 = 2 * j;
            float2 a = A[LP(i0)], b = A[LP(i0 + 1)];
            A[LP(i0)]     = make_float2(a.x + b.x, a.y + b.y);
            A[LP(i0 + 1)] = make_float2(a.x - b.x, a.y - b.y);
        }
        __syncthreads();
        s = 1;
    }
    for (; s < logN; s += 2) {    // fused stages (s, s+1)
        const int Ns = 1 << s;
        for (int g = tid; g < (N >> 2); g += nthr) {
            int k = g & (Ns - 1);
            int base = ((g >> s) << (s + 2)) | k;
            float2 a0 = A[LP(base)];
            float2 a1 = A[LP(base + Ns)];
            float2 a2 = A[LP(base + 2*Ns)];
            float2 a3 = A[LP(base + 3*Ns)];
            float ang1 = (float)SGN * PI_F * (float)k / (float)Ns;
            float sn1, cs1; __sincosf(ang1, &sn1, &cs1);
            float2 t = make_float2(cs1*a1.x - sn1*a1.y, cs1*a1.y + sn1*a1.x);
            float2 b0 = make_float2(a0.x + t.x, a0.y + t.y);
            float2 b1 = make_float2(a0.x - t.x, a0.y - t.y);
            t = make_float2(cs1*a3.x - sn1*a3.y, cs1*a3.y + sn1*a3.x);
            float2 b2 = make_float2(a2.x + t.x, a2.y + t.y);
            float2 b3 = make_float2(a2.x - t.x, a2.y - t.y);
            float ang2 = (float)SGN * PI_F * (float)k / (float)(2 * Ns);
            float sn2, cs2; __sincosf(ang2, &sn2, &cs2);
            t = make_float2(cs2*b2.x - sn2*b2.y, cs2*b2.y + sn2*b2.x);
            A[LP(base)]        = make_float2(b0.x + t.x, b0.y + t.y);
            A[LP(base + 2*Ns)] = make_float2(b0.x - t.x, b0.y - t.y);
            float c2p, s2p;                   // w2' = w2 * e^{SGN*i*pi/2}
            if (SGN < 0) { c2p = sn2; s2p = -cs2; } else { c2p = -sn2; s2p = cs2; }
            t = make_float2(c2p*b3.x - s2p*b3.y, c2p*b3.y + s2p*b3.x);
            A[LP(base + Ns)]   = make_float2(b1.x + t.x, b1.y + t.y);
            A[LP(base + 3*Ns)] = make_float2(b1.x - t.x, b1.y - t.y);
        }
        __syncthreads();
    }
}

// ---------------- K0: transpose W [512][256] -> Wt [256][512] ----------------
__global__ void k0_transposeW(const float* __restrict__ W, float* __restrict__ Wt)
{
    __shared__ float t[32][33];
    int c0 = blockIdx.x * 32, r0 = blockIdx.y * 32;
    int tx = threadIdx.x, ty = threadIdx.y;
    for (int i = ty; i < 32; i += 8)
        t[i][tx] = W[(size_t)(r0 + i) * 256 + c0 + tx];
    __syncthreads();
    for (int i = ty; i < 32; i += 8)
        Wt[(size_t)(c0 + i) * 512 + r0 + tx] = t[tx][i];
}

// ---------------- K1: NPLR kernel generation (f64) ----------------
__global__ void k1_kergen(const float* __restrict__ log_dt, const float* __restrict__ wlr,
                          const float* __restrict__ wim, const float* __restrict__ Pre,
                          const float* __restrict__ Pim, const float* __restrict__ Bre,
                          const float* __restrict__ Bim, const float* __restrict__ Cre,
                          const float* __restrict__ Cim, float2* __restrict__ kf_out)
{
    int h = blockIdx.x;
    int f = blockIdx.y * 256 + threadIdx.x;
    if (f > 1024) return;
    double dt = exp((double)log_dt[h]);
    double th = -2.0 * PI_D * (double)f / 2048.0;
    double ox = cos(th), oy = sin(th);
    cd onep{1.0 + ox, oy};
    cd z = cdivd(cd{2.0*(1.0 - ox), -2.0*oy}, onep);
    cd r00{0,0}, r01{0,0}, r02{0,0}, r10{0,0}, r11{0,0}, r12{0,0};
    const int base = h * 32;
    for (int n = 0; n < 32; ++n) {
        double wre = -exp((double)wlr[base+n]) * dt;
        double wi  = (double)wim[base+n] * dt;
        cd i1 = cdivd(cd{1.0, 0.0}, cd{z.x - wre, z.y - wi});
        cd i2 = cdivd(cd{1.0, 0.0}, cd{z.x - wre, z.y + wi});
        cd B0{(double)Bre[base+n], (double)Bim[base+n]};
        cd P0{(double)Pre[base+n], (double)Pim[base+n]};
        cd C0{(double)Cre[base+n], (double)Cim[base+n]};
        cd C1{(double)Cre[8192+base+n], (double)Cim[8192+base+n]};
        cd C2{P0.x, -P0.y};
        r00 = caccum(r00, cmuld(B0, C0), i1, i2);
        r01 = caccum(r01, cmuld(B0, C1), i1, i2);
        r02 = caccum(r02, cmuld(B0, C2), i1, i2);
        r10 = caccum(r10, cmuld(P0, C0), i1, i2);
        r11 = caccum(r11, cmuld(P0, C1), i1, i2);
        r12 = caccum(r12, cmuld(P0, C2), i1, i2);
    }
    r00.x *= dt; r00.y *= dt; r01.x *= dt; r01.y *= dt; r02.x *= dt; r02.y *= dt;
    r10.x *= dt; r10.y *= dt; r11.x *= dt; r11.y *= dt; r12.x *= dt; r12.y *= dt;
    cd den{1.0 + r12.x, r12.y};
    cd fac = cdivd(cd{2.0, 0.0}, onep);
    cd t0 = cdivd(cmuld(r02, r10), den);
    cd k0{r00.x - t0.x, r00.y - t0.y};
    k0 = cmuld(k0, fac);
    cd t1 = cdivd(cmuld(r02, r11), den);
    cd k1{r01.x - t1.x, r01.y - t1.y};
    k1 = cmuld(k1, fac);
    kf_out[(size_t)h * 1025 + f]         = make_float2((float)k0.x, (float)k0.y);
    kf_out[(size_t)(256 + h) * 1025 + f] = make_float2((float)k1.x, (float)k1.y);
}

// ---------------- K2: packed irfft(ch0,ch1) -> kk -> fft4096 -> kf ----------
// grid 256 = h. Packed: ifft(E0 + i*E1) = k0 + i*k1 (exact, E0/E1 hermitian).
__global__ __launch_bounds__(256) void k2_kernelfft(const float2* __restrict__ kfin,
                                                    float2* __restrict__ kfout)
{
    __shared__ float2 A2[2176];   // 2048 padded
    __shared__ float2 A4[4352];   // 4096 padded
    int h = blockIdx.x, tid = threadIdx.x;
    const float2* s0 = kfin + (size_t)h * 1025;
    const float2* s1 = kfin + (size_t)(256 + h) * 1025;
    for (int j = tid; j < 2048; j += 256) {
        float2 q0, q1;
        if (j == 0)          { q0 = s0[0];    q0.y = 0.0f; q1 = s1[0];    q1.y = 0.0f; }
        else if (j < 1024)   { q0 = s0[j];                 q1 = s1[j]; }
        else if (j == 1024)  { q0 = s0[1024]; q0.y = 0.0f; q1 = s1[1024]; q1.y = 0.0f; }
        else { float2 t0 = s0[2048 - j], t1 = s1[2048 - j];
               q0 = make_float2(t0.x, -t0.y); q1 = make_float2(t1.x, -t1.y); }
        A2[LP(j)] = make_float2(q0.x - q1.y, q0.y + q1.x);   // E0 + i*E1
    }
    fft_fused<+1>(A2, 2048, 11, tid, 256);
    const float scl = 1.0f / 2048.0f;
    for (int j = tid; j < 2048; j += 256) {
        float2 v = A2[LP(j)];
        A4[LP(j)]        = make_float2(v.x * scl, 0.0f);     // kk[j]      = k0[j]
        A4[LP(4095 - j)] = make_float2(v.y * scl, 0.0f);     // kk[4095-j] = k1[j]
    }
    fft_fused<-1>(A4, 4096, 12, tid, 256);
    for (int F = tid; F <= 2048; F += 256)
        kfout[(size_t)h * 2049 + F] = A4[LP(F)];
}

// ---------------- K3: transpose x (2048 x 4096) -> u (4096 x 2048) ----------
__global__ void k3_transpose(const float* __restrict__ x, float* __restrict__ u)
{
    __shared__ float tile[32][33];
    int p0 = blockIdx.x * 32;
    int l0 = blockIdx.y * 32;
    int tx = threadIdx.x, ty = threadIdx.y;
    for (int i = ty; i < 32; i += 8)
        tile[i][tx] = x[(size_t)(l0 + i) * 4096 + p0 + tx];
    __syncthreads();
    for (int i = ty; i < 32; i += 8)
        u[(size_t)(p0 + i) * 2048 + l0 + tx] = tile[tx][i];
}

// ---------------- K4: pair-packed FFT conv + D-skip + GELU ------------------
// grid 2048 = bp*256 + h (bp = batch pair). Exact by linearity: the filter is
// real, so conv results of u0,u1 sit in Re,Im of the packed transform.
__global__ __launch_bounds__(256) void k4_conv(const float* __restrict__ u,
        const float2* __restrict__ kf, const float* __restrict__ Dp, float* __restrict__ yg)
{
    __shared__ float2 A[4352];
    int h  = blockIdx.x & 255;
    int bp = blockIdx.x >> 8;
    int tid = threadIdx.x;
    const float* u0 = u + (size_t)((2*bp)   * 256 + h) * 2048;
    const float* u1 = u + (size_t)((2*bp+1) * 256 + h) * 2048;
    for (int j = tid; j < 2048; j += 256) {
        A[LP(j)]        = make_float2(u0[j], u1[j]);
        A[LP(2048 + j)] = make_float2(0.0f, 0.0f);
    }
    fft_fused<-1>(A, 4096, 12, tid, 256);
    const float2* kfh = kf + (size_t)h * 2049;
    for (int f = tid; f < 4096; f += 256) {
        float2 K;
        if (f <= 2048) K = kfh[f];
        else { float2 t = kfh[4096 - f]; K = make_float2(t.x, -t.y); }
        A[LP(f)] = cmulf(A[LP(f)], K);
    }
    fft_fused<+1>(A, 4096, 12, tid, 256);
    float d = Dp[h];
    float* o0 = yg + (size_t)((2*bp)   * 256 + h) * 2048;
    float* o1 = yg + (size_t)((2*bp+1) * 256 + h) * 2048;
    const float iscl = 1.0f / 4096.0f;
    for (int j = tid; j < 2048; j += 256) {
        float2 Y = A[LP(j)];
        float y0 = Y.x * iscl + d * u0[j];
        float y1 = Y.y * iscl + d * u1[j];
        o0[j] = 0.5f * y0 * (1.0f + erff(y0 * 0.70710678118654752f));
        o1[j] = 0.5f * y1 * (1.0f + erff(y1 * 0.70710678118654752f));
    }
}

// ---------------- K5: y2 = W@yg + bout ; GLU ; in-place ---------------------
// grid (32 l-tiles of 64, 16 b). 256 thr = 64 P-threads x 4 l-groups.
// Thread: A-rows 4pt..4pt+3, B-rows 256+4pt.., 16 l  -> 128 f32 acc.
__global__ __launch_bounds__(256) void k5_gemm_glu(float* __restrict__ yg,
        const float* __restrict__ Wt, const float* __restrict__ bout)
{
    __shared__ float yt[256][68];    // [hh][l], row stride 68 (16B-aligned, conflict-free)
    int b  = blockIdx.y;
    int l0 = blockIdx.x * 64;
    int tid = threadIdx.x;
    int pt = tid & 63, lg = tid >> 6;
    for (int i = tid; i < 256 * 16; i += 256) {
        int hh = i >> 4, lc = i & 15;
        float4 v = *(const float4*)&yg[(size_t)(b * 256 + hh) * 2048 + l0 + lc * 4];
        *(float4*)&yt[hh][lc * 4] = v;
    }
    __syncthreads();
    float4 aA[4][4], aB[4][4];
    #pragma unroll
    for (int r = 0; r < 4; ++r)
        #pragma unroll
        for (int q = 0; q < 4; ++q) {
            aA[r][q] = make_float4(0,0,0,0);
            aB[r][q] = make_float4(0,0,0,0);
        }
    const int lbase = lg * 16;
    for (int hh = 0; hh < 256; ++hh) {
        float4 wA = *(const float4*)&Wt[(size_t)hh * 512 + 4 * pt];
        float4 wB = *(const float4*)&Wt[(size_t)hh * 512 + 256 + 4 * pt];
        float4 y0 = *(const float4*)&yt[hh][lbase];
        float4 y1 = *(const float4*)&yt[hh][lbase + 4];
        float4 y2 = *(const float4*)&yt[hh][lbase + 8];
        float4 y3 = *(const float4*)&yt[hh][lbase + 12];
        const float wa[4] = {wA.x, wA.y, wA.z, wA.w};
        const float wb[4] = {wB.x, wB.y, wB.z, wB.w};
        #pragma unroll
        for (int r = 0; r < 4; ++r) {
            float a = wa[r], c = wb[r];
            aA[r][0].x += a*y0.x; aA[r][0].y += a*y0.y; aA[r][0].z += a*y0.z; aA[r][0].w += a*y0.w;
            aA[r][1].x += a*y1.x; aA[r][1].y += a*y1.y; aA[r][1].z += a*y1.z; aA[r][1].w += a*y1.w;
            aA[r][2].x += a*y2.x; aA[r][2].y += a*y2.y; aA[r][2].z += a*y2.z; aA[r][2].w += a*y2.w;
            aA[r][3].x += a*y3.x; aA[r][3].y += a*y3.y; aA[r][3].z += a*y3.z; aA[r][3].w += a*y3.w;
            aB[r][0].x += c*y0.x; aB[r][0].y += c*y0.y; aB[r][0].z += c*y0.z; aB[r][0].w += c*y0.w;
            aB[r][1].x += c*y1.x; aB[r][1].y += c*y1.y; aB[r][1].z += c*y1.z; aB[r][1].w += c*y1.w;
            aB[r][2].x += c*y2.x; aB[r][2].y += c*y2.y; aB[r][2].z += c*y2.z; aB[r][2].w += c*y2.w;
            aB[r][3].x += c*y3.x; aB[r][3].y += c*y3.y; aB[r][3].z += c*y3.z; aB[r][3].w += c*y3.w;
        }
    }
    int Pr = 4 * pt;
    float4 ba4 = *(const float4*)&bout[Pr];
    float4 bb4 = *(const float4*)&bout[256 + Pr];
    const float ba[4] = {ba4.x, ba4.y, ba4.z, ba4.w};
    const float bb[4] = {bb4.x, bb4.y, bb4.z, bb4.w};
    #pragma unroll
    for (int r = 0; r < 4; ++r) {
        float* o = yg + (size_t)(b * 256 + Pr + r) * 2048 + l0 + lbase;
        #pragma unroll
        for (int q = 0; q < 4; ++q) {
            float4 A4 = aA[r][q], B4 = aB[r][q], g4;
            g4.x = (A4.x + ba[r]) / (1.0f + expf(-(B4.x + bb[r])));
            g4.y = (A4.y + ba[r]) / (1.0f + expf(-(B4.y + bb[r])));
            g4.z = (A4.z + ba[r]) / (1.0f + expf(-(B4.z + bb[r])));
            g4.w = (A4.w + ba[r]) / (1.0f + expf(-(B4.w + bb[r])));
            *(float4*)(o + q * 4) = g4;
        }
    }
}

// ---------------- K6: residual + LayerNorm + coalesced f32 store ------------
__global__ __launch_bounds__(256) void k6_ln(const float* __restrict__ g, const float* __restrict__ u,
        const float* __restrict__ gamma, const float* __restrict__ beta,
        float* __restrict__ out)
{
    __shared__ float ts[64][257];
    __shared__ float redS[4][64], redQ[4][64], gam[256], bet[256];
    int b  = blockIdx.y;
    int l0 = blockIdx.x * 64;
    int tid = threadIdx.x;
    int l = tid & 63, hq = tid >> 6;
    gam[tid] = gamma[tid]; bet[tid] = beta[tid];
    float v[64];
    float s = 0.0f, q2 = 0.0f;
    const float* gp = g + (size_t)(b * 256 + hq * 64) * 2048 + l0 + l;
    const float* up = u + (size_t)(b * 256 + hq * 64) * 2048 + l0 + l;
    #pragma unroll
    for (int hh = 0; hh < 64; ++hh) {
        float val = gp[(size_t)hh * 2048] + up[(size_t)hh * 2048];
        v[hh] = val; s += val; q2 += val * val;
    }
    redS[hq][l] = s; redQ[hq][l] = q2;
    __syncthreads();
    float st = redS[0][l] + redS[1][l] + redS[2][l] + redS[3][l];
    float qt = redQ[0][l] + redQ[1][l] + redQ[2][l] + redQ[3][l];
    float mu = st * (1.0f / 256.0f);
    float var = qt * (1.0f / 256.0f) - mu * mu;
    float rstd = rsqrtf(var + 1e-5f);
    #pragma unroll
    for (int hh = 0; hh < 64; ++hh) {
        int hdx = hq * 64 + hh;
        ts[l][hdx] = (v[hh] - mu) * rstd * gam[hdx] + bet[hdx];
    }
    __syncthreads();
    for (int i = tid; i < 64 * 256; i += 256) {
        int r = i >> 8, c = i & 255;
        out[(size_t)((l0 + r) * 16 + b) * 256 + c] = ts[r][c];
    }
}

// ---------------- launch ----------------
extern "C" void kernel_launch(void* const* d_in, const int* in_sizes, int n_in,
                              void* d_out, int out_size, void* d_ws, size_t ws_size,
                              hipStream_t stream)
{
    (void)in_sizes; (void)n_in; (void)out_size; (void)ws_size;
    const float* x      = (const float*)d_in[0];
    const float* log_dt = (const float*)d_in[1];
    const float* wlr    = (const float*)d_in[2];
    const float* wim    = (const float*)d_in[3];
    const float* Pre    = (const float*)d_in[4];
    const float* Pim    = (const float*)d_in[5];
    const float* Bre    = (const float*)d_in[6];
    const float* Bim    = (const float*)d_in[7];
    const float* Cre    = (const float*)d_in[8];
    const float* Cim    = (const float*)d_in[9];
    const float* Dp     = (const float*)d_in[10];
    const float* Wout   = (const float*)d_in[11];
    const float* bout   = (const float*)d_in[12];
    const float* gamma  = (const float*)d_in[13];
    const float* beta   = (const float*)d_in[14];

    // ws: 64MB (u, yg). Scratch in d_out (33.5MB): kF + kfo + Wt = 8.9MB,
    // all dead before k6 overwrites the full output.
    float* ws  = (float*)d_ws;
    float* u   = ws;                 // 32MB (B,H,L)
    float* yg  = ws + 8388608;       // 32MB (B,H,L)
    char*  ob  = (char*)d_out;
    float2* kF  = (float2*)(ob);               // 4,198,400 B
    float2* kfo = (float2*)(ob + 4198400);     // 4,196,352 B
    float*  Wt  = (float*) (ob + 8394752);     //   524,288 B (ends 8.9MB)

    k0_transposeW<<<dim3(8, 16), dim3(32, 8), 0, stream>>>(Wout, Wt);
    k1_kergen<<<dim3(256, 5), 256, 0, stream>>>(log_dt, wlr, wim, Pre, Pim, Bre, Bim, Cre, Cim, kF);
    k2_kernelfft<<<dim3(256), 256, 0, stream>>>(kF, kfo);
    k3_transpose<<<dim3(128, 64), dim3(32, 8), 0, stream>>>(x, u);
    k4_conv<<<dim3(2048), 256, 0, stream>>>(u, kfo, Dp, yg);
    k5_gemm_glu<<<dim3(32, 16), 256, 0, stream>>>(yg, Wt, bout);
    k6_ln<<<dim3(32, 16), 256, 0, stream>>>(yg, u, gamma, beta, (float*)d_out);
}

// Round 9
// 275.348 us; speedup vs baseline: 1.6649x; 1.1532x over previous
//
#include <hip/hip_runtime.h>

// S4 (SSSD) layer: L=2048, B=16, H=256, N2=32. Output f32.
// R9: k5 GEMM+GLU rewritten on MFMA bf16 (16x16x32), f32 accumulate.
// k0 converts Wout f32 -> bf16 row-major. k4 gains register u-cache.
// Rest identical to R8 (pair-packed padded FFTs).

#define PI_F 3.14159265358979323846f
#define PI_D 3.14159265358979323846
#define LP(i) ((i) + ((i) >> 4))    // LDS pad: +1 slot per 16 elements

typedef __attribute__((ext_vector_type(8))) short bf16x8;
typedef __attribute__((ext_vector_type(4))) float f32x4;

// ---------------- complex helpers ----------------
struct cd { double x, y; };
__device__ __forceinline__ cd cmuld(cd a, cd b) {
    return cd{a.x*b.x - a.y*b.y, a.x*b.y + a.y*b.x};
}
__device__ __forceinline__ cd cdivd(cd a, cd b) {
    double inv = 1.0 / (b.x*b.x + b.y*b.y);
    return cd{(a.x*b.x + a.y*b.y) * inv, (a.y*b.x - a.x*b.y) * inv};
}
__device__ __forceinline__ cd caccum(cd r, cd v, cd i1, cd i2) {
    r.x += v.x*i1.x - v.y*i1.y + v.x*i2.x + v.y*i2.y;
    r.y += v.x*i1.y + v.y*i1.x + v.x*i2.y - v.y*i2.x;
    return r;
}
__device__ __forceinline__ float2 cmulf(float2 a, float2 b) {
    return make_float2(a.x*b.x - a.y*b.y, a.x*b.y + a.y*b.x);
}
__device__ __forceinline__ unsigned short f2bf(float f) { // RNE f32->bf16 bits
    unsigned int u = __float_as_uint(f);
    u += 0x7fffu + ((u >> 16) & 1u);
    return (unsigned short)(u >> 16);
}

// -------- in-place DIT FFT, fused double-stages, padded LDS addressing ------
template<int SGN>
__device__ __forceinline__ void fft_fused(float2* A, int N, int logN,
                                          int tid, int nthr) {
    __syncthreads();
    for (int j = tid; j < N; j += nthr) {
        int r = (int)(__brev((unsigned)j) >> (32 - logN));
        if (r > j) { float2 t = A[LP(j)]; A[LP(j)] = A[LP(r)]; A[LP(r)] = t; }
    }
    __syncthreads();
    int s = 0;
    if (logN & 1) {
        for (int j = tid; j < (N >> 1); j += nthr) {
            int i0 = 2 * j;
            float2 a = A[LP(i0)], b = A[LP(i0 + 1)];
            A[LP(i0)]     = make_float2(a.x + b.x, a.y + b.y);
            A[LP(i0 + 1)] = make_float2(a.x - b.x, a.y - b.y);
        }
        __syncthreads();
        s = 1;
    }
    for (; s < logN; s += 2) {
        const int Ns = 1 << s;
        for (int g = tid; g < (N >> 2); g += nthr) {
            int k = g & (Ns - 1);
            int base = ((g >> s) << (s + 2)) | k;
            float2 a0 = A[LP(base)];
            float2 a1 = A[LP(base + Ns)];
            float2 a2 = A[LP(base + 2*Ns)];
            float2 a3 = A[LP(base + 3*Ns)];
            float ang1 = (float)SGN * PI_F * (float)k / (float)Ns;
            float sn1, cs1; __sincosf(ang1, &sn1, &cs1);
            float2 t = make_float2(cs1*a1.x - sn1*a1.y, cs1*a1.y + sn1*a1.x);
            float2 b0 = make_float2(a0.x + t.x, a0.y + t.y);
            float2 b1 = make_float2(a0.x - t.x, a0.y - t.y);
            t = make_float2(cs1*a3.x - sn1*a3.y, cs1*a3.y + sn1*a3.x);
            float2 b2 = make_float2(a2.x + t.x, a2.y + t.y);
            float2 b3 = make_float2(a2.x - t.x, a2.y - t.y);
            float ang2 = (float)SGN * PI_F * (float)k / (float)(2 * Ns);
            float sn2, cs2; __sincosf(ang2, &sn2, &cs2);
            t = make_float2(cs2*b2.x - sn2*b2.y, cs2*b2.y + sn2*b2.x);
            A[LP(base)]        = make_float2(b0.x + t.x, b0.y + t.y);
            A[LP(base + 2*Ns)] = make_float2(b0.x - t.x, b0.y - t.y);
            float c2p, s2p;
            if (SGN < 0) { c2p = sn2; s2p = -cs2; } else { c2p = -sn2; s2p = cs2; }
            t = make_float2(c2p*b3.x - s2p*b3.y, c2p*b3.y + s2p*b3.x);
            A[LP(base + Ns)]   = make_float2(b1.x + t.x, b1.y + t.y);
            A[LP(base + 3*Ns)] = make_float2(b1.x - t.x, b1.y - t.y);
        }
        __syncthreads();
    }
}

// ---------------- K0: convert W [512][256] f32 -> bf16 (row-major) ----------
__global__ void k0_convW(const float* __restrict__ W, unsigned short* __restrict__ Wb)
{
    int i = blockIdx.x * 256 + threadIdx.x;
    if (i < 512 * 256) Wb[i] = f2bf(W[i]);
}

// ---------------- K1: NPLR kernel generation (f64) ----------------
__global__ void k1_kergen(const float* __restrict__ log_dt, const float* __restrict__ wlr,
                          const float* __restrict__ wim, const float* __restrict__ Pre,
                          const float* __restrict__ Pim, const float* __restrict__ Bre,
                          const float* __restrict__ Bim, const float* __restrict__ Cre,
                          const float* __restrict__ Cim, float2* __restrict__ kf_out)
{
    int h = blockIdx.x;
    int f = blockIdx.y * 256 + threadIdx.x;
    if (f > 1024) return;
    double dt = exp((double)log_dt[h]);
    double th = -2.0 * PI_D * (double)f / 2048.0;
    double ox = cos(th), oy = sin(th);
    cd onep{1.0 + ox, oy};
    cd z = cdivd(cd{2.0*(1.0 - ox), -2.0*oy}, onep);
    cd r00{0,0}, r01{0,0}, r02{0,0}, r10{0,0}, r11{0,0}, r12{0,0};
    const int base = h * 32;
    for (int n = 0; n < 32; ++n) {
        double wre = -exp((double)wlr[base+n]) * dt;
        double wi  = (double)wim[base+n] * dt;
        cd i1 = cdivd(cd{1.0, 0.0}, cd{z.x - wre, z.y - wi});
        cd i2 = cdivd(cd{1.0, 0.0}, cd{z.x - wre, z.y + wi});
        cd B0{(double)Bre[base+n], (double)Bim[base+n]};
        cd P0{(double)Pre[base+n], (double)Pim[base+n]};
        cd C0{(double)Cre[base+n], (double)Cim[base+n]};
        cd C1{(double)Cre[8192+base+n], (double)Cim[8192+base+n]};
        cd C2{P0.x, -P0.y};
        r00 = caccum(r00, cmuld(B0, C0), i1, i2);
        r01 = caccum(r01, cmuld(B0, C1), i1, i2);
        r02 = caccum(r02, cmuld(B0, C2), i1, i2);
        r10 = caccum(r10, cmuld(P0, C0), i1, i2);
        r11 = caccum(r11, cmuld(P0, C1), i1, i2);
        r12 = caccum(r12, cmuld(P0, C2), i1, i2);
    }
    r00.x *= dt; r00.y *= dt; r01.x *= dt; r01.y *= dt; r02.x *= dt; r02.y *= dt;
    r10.x *= dt; r10.y *= dt; r11.x *= dt; r11.y *= dt; r12.x *= dt; r12.y *= dt;
    cd den{1.0 + r12.x, r12.y};
    cd fac = cdivd(cd{2.0, 0.0}, onep);
    cd t0 = cdivd(cmuld(r02, r10), den);
    cd k0{r00.x - t0.x, r00.y - t0.y};
    k0 = cmuld(k0, fac);
    cd t1 = cdivd(cmuld(r02, r11), den);
    cd k1{r01.x - t1.x, r01.y - t1.y};
    k1 = cmuld(k1, fac);
    kf_out[(size_t)h * 1025 + f]         = make_float2((float)k0.x, (float)k0.y);
    kf_out[(size_t)(256 + h) * 1025 + f] = make_float2((float)k1.x, (float)k1.y);
}

// ---------------- K2: packed irfft(ch0,ch1) -> kk -> fft4096 -> kf ----------
__global__ __launch_bounds__(256) void k2_kernelfft(const float2* __restrict__ kfin,
                                                    float2* __restrict__ kfout)
{
    __shared__ float2 A2[2176];
    __shared__ float2 A4[4352];
    int h = blockIdx.x, tid = threadIdx.x;
    const float2* s0 = kfin + (size_t)h * 1025;
    const float2* s1 = kfin + (size_t)(256 + h) * 1025;
    for (int j = tid; j < 2048; j += 256) {
        float2 q0, q1;
        if (j == 0)          { q0 = s0[0];    q0.y = 0.0f; q1 = s1[0];    q1.y = 0.0f; }
        else if (j < 1024)   { q0 = s0[j];                 q1 = s1[j]; }
        else if (j == 1024)  { q0 = s0[1024]; q0.y = 0.0f; q1 = s1[1024]; q1.y = 0.0f; }
        else { float2 t0 = s0[2048 - j], t1 = s1[2048 - j];
               q0 = make_float2(t0.x, -t0.y); q1 = make_float2(t1.x, -t1.y); }
        A2[LP(j)] = make_float2(q0.x - q1.y, q0.y + q1.x);   // E0 + i*E1
    }
    fft_fused<+1>(A2, 2048, 11, tid, 256);
    const float scl = 1.0f / 2048.0f;
    for (int j = tid; j < 2048; j += 256) {
        float2 v = A2[LP(j)];
        A4[LP(j)]        = make_float2(v.x * scl, 0.0f);
        A4[LP(4095 - j)] = make_float2(v.y * scl, 0.0f);
    }
    fft_fused<-1>(A4, 4096, 12, tid, 256);
    for (int F = tid; F <= 2048; F += 256)
        kfout[(size_t)h * 2049 + F] = A4[LP(F)];
}

// ---------------- K3: transpose x (2048 x 4096) -> u (4096 x 2048) ----------
__global__ void k3_transpose(const float* __restrict__ x, float* __restrict__ u)
{
    __shared__ float tile[32][33];
    int p0 = blockIdx.x * 32;
    int l0 = blockIdx.y * 32;
    int tx = threadIdx.x, ty = threadIdx.y;
    for (int i = ty; i < 32; i += 8)
        tile[i][tx] = x[(size_t)(l0 + i) * 4096 + p0 + tx];
    __syncthreads();
    for (int i = ty; i < 32; i += 8)
        u[(size_t)(p0 + i) * 2048 + l0 + tx] = tile[tx][i];
}

// ---------------- K4: pair-packed FFT conv + D-skip + GELU ------------------
__global__ __launch_bounds__(256) void k4_conv(const float* __restrict__ u,
        const float2* __restrict__ kf, const float* __restrict__ Dp, float* __restrict__ yg)
{
    __shared__ float2 A[4352];
    int h  = blockIdx.x & 255;
    int bp = blockIdx.x >> 8;
    int tid = threadIdx.x;
    const float* u0 = u + (size_t)((2*bp)   * 256 + h) * 2048;
    const float* u1 = u + (size_t)((2*bp+1) * 256 + h) * 2048;
    float uv0[8], uv1[8];
    #pragma unroll
    for (int jj = 0; jj < 8; ++jj) {
        int j = jj * 256 + tid;
        uv0[jj] = u0[j]; uv1[jj] = u1[j];
        A[LP(j)]        = make_float2(uv0[jj], uv1[jj]);
        A[LP(2048 + j)] = make_float2(0.0f, 0.0f);
    }
    fft_fused<-1>(A, 4096, 12, tid, 256);
    const float2* kfh = kf + (size_t)h * 2049;
    for (int f = tid; f < 4096; f += 256) {
        float2 K;
        if (f <= 2048) K = kfh[f];
        else { float2 t = kfh[4096 - f]; K = make_float2(t.x, -t.y); }
        A[LP(f)] = cmulf(A[LP(f)], K);
    }
    fft_fused<+1>(A, 4096, 12, tid, 256);
    float d = Dp[h];
    float* o0 = yg + (size_t)((2*bp)   * 256 + h) * 2048;
    float* o1 = yg + (size_t)((2*bp+1) * 256 + h) * 2048;
    const float iscl = 1.0f / 4096.0f;
    #pragma unroll
    for (int jj = 0; jj < 8; ++jj) {
        int j = jj * 256 + tid;
        float2 Y = A[LP(j)];
        float y0 = Y.x * iscl + d * uv0[jj];
        float y1 = Y.y * iscl + d * uv1[jj];
        o0[j] = 0.5f * y0 * (1.0f + erff(y0 * 0.70710678118654752f));
        o1[j] = 0.5f * y1 * (1.0f + erff(y1 * 0.70710678118654752f));
    }
}

// ---------------- K5: MFMA bf16 GEMM + GLU, in-place ------------------------
// grid (32 l-tiles of 64, 16 b). 4 waves; wave w owns l-sub [16w,16w+16),
// all 32 P-tiles (tiles 0..15 = y2a rows 0..255, 16..31 = gate rows 256..511).
// D[r][c]: r = P-row, c = l-col. A = Wb[P][k] (global/L2), B = yt[l][k] (LDS).
__global__ __launch_bounds__(256, 2) void k5_gemm_glu(float* __restrict__ yg,
        const unsigned short* __restrict__ Wb, const float* __restrict__ bout)
{
    __shared__ short yt[64][264];     // bf16 y-tile, row stride 528B (16B-aligned)
    __shared__ float bo[512];
    int b  = blockIdx.y;
    int l0 = blockIdx.x * 64;
    int tid = threadIdx.x;
    int lane = tid & 63, w = tid >> 6;
    int cc = lane & 15, gg = lane >> 4;
    bo[tid] = bout[tid]; bo[tid + 256] = bout[tid + 256];
    // stage y-tile: coalesced f32 read, bf16 write [l][h]
    int li = tid & 63;
    #pragma unroll 4
    for (int it = 0; it < 64; ++it) {
        int hh = (tid >> 6) + it * 4;
        float v = yg[(size_t)(b * 256 + hh) * 2048 + l0 + li];
        yt[li][hh] = (short)f2bf(v);
    }
    __syncthreads();
    f32x4 acc[32];
    #pragma unroll
    for (int t = 0; t < 32; ++t) acc[t] = (f32x4){0.f, 0.f, 0.f, 0.f};
    const short* brow = &yt[16 * w + cc][0];
    #pragma unroll
    for (int ks = 0; ks < 8; ++ks) {
        bf16x8 bfrag = *(const bf16x8*)(brow + ks * 32 + gg * 8);
        const unsigned short* wp = Wb + (size_t)cc * 256 + ks * 32 + gg * 8;
        #pragma unroll
        for (int t = 0; t < 32; ++t) {
            bf16x8 afrag = *(const bf16x8*)(wp + (size_t)t * 16 * 256);
            acc[t] = __builtin_amdgcn_mfma_f32_16x16x32_bf16(afrag, bfrag, acc[t], 0, 0, 0);
        }
    }
    // epilogue: GLU pairs (tile t, tile t+16), scattered 4B stores (64B bursts)
    #pragma unroll
    for (int t = 0; t < 16; ++t) {
        #pragma unroll
        for (int r = 0; r < 4; ++r) {
            int P = t * 16 + gg * 4 + r;
            float ya = acc[t][r] + bo[P];
            float gb = acc[t + 16][r] + bo[256 + P];
            float g = ya / (1.0f + expf(-gb));
            yg[(size_t)(b * 256 + P) * 2048 + l0 + 16 * w + cc] = g;
        }
    }
}

// ---------------- K6: residual + LayerNorm + coalesced f32 store ------------
__global__ __launch_bounds__(256) void k6_ln(const float* __restrict__ g, const float* __restrict__ u,
        const float* __restrict__ gamma, const float* __restrict__ beta,
        float* __restrict__ out)
{
    __shared__ float ts[64][257];
    __shared__ float redS[4][64], redQ[4][64], gam[256], bet[256];
    int b  = blockIdx.y;
    int l0 = blockIdx.x * 64;
    int tid = threadIdx.x;
    int l = tid & 63, hq = tid >> 6;
    gam[tid] = gamma[tid]; bet[tid] = beta[tid];
    float v[64];
    float s = 0.0f, q2 = 0.0f;
    const float* gp = g + (size_t)(b * 256 + hq * 64) * 2048 + l0 + l;
    const float* up = u + (size_t)(b * 256 + hq * 64) * 2048 + l0 + l;
    #pragma unroll
    for (int hh = 0; hh < 64; ++hh) {
        float val = gp[(size_t)hh * 2048] + up[(size_t)hh * 2048];
        v[hh] = val; s += val; q2 += val * val;
    }
    redS[hq][l] = s; redQ[hq][l] = q2;
    __syncthreads();
    float st = redS[0][l] + redS[1][l] + redS[2][l] + redS[3][l];
    float qt = redQ[0][l] + redQ[1][l] + redQ[2][l] + redQ[3][l];
    float mu = st * (1.0f / 256.0f);
    float var = qt * (1.0f / 256.0f) - mu * mu;
    float rstd = rsqrtf(var + 1e-5f);
    #pragma unroll
    for (int hh = 0; hh < 64; ++hh) {
        int hdx = hq * 64 + hh;
        ts[l][hdx] = (v[hh] - mu) * rstd * gam[hdx] + bet[hdx];
    }
    __syncthreads();
    for (int i = tid; i < 64 * 256; i += 256) {
        int r = i >> 8, c = i & 255;
        out[(size_t)((l0 + r) * 16 + b) * 256 + c] = ts[r][c];
    }
}

// ---------------- launch ----------------
extern "C" void kernel_launch(void* const* d_in, const int* in_sizes, int n_in,
                              void* d_out, int out_size, void* d_ws, size_t ws_size,
                              hipStream_t stream)
{
    (void)in_sizes; (void)n_in; (void)out_size; (void)ws_size;
    const float* x      = (const float*)d_in[0];
    const float* log_dt = (const float*)d_in[1];
    const float* wlr    = (const float*)d_in[2];
    const float* wim    = (const float*)d_in[3];
    const float* Pre    = (const float*)d_in[4];
    const float* Pim    = (const float*)d_in[5];
    const float* Bre    = (const float*)d_in[6];
    const float* Bim    = (const float*)d_in[7];
    const float* Cre    = (const float*)d_in[8];
    const float* Cim    = (const float*)d_in[9];
    const float* Dp     = (const float*)d_in[10];
    const float* Wout   = (const float*)d_in[11];
    const float* bout   = (const float*)d_in[12];
    const float* gamma  = (const float*)d_in[13];
    const float* beta   = (const float*)d_in[14];

    // ws: 64MB (u, yg). Scratch in d_out (33.5MB): kF + kfo + Wb = 8.7MB,
    // all dead before k6 overwrites the full output.
    float* ws  = (float*)d_ws;
    float* u   = ws;                 // 32MB (B,H,L)
    float* yg  = ws + 8388608;       // 32MB (B,H,L)
    char*  ob  = (char*)d_out;
    float2* kF  = (float2*)(ob);                       // 4,198,400 B
    float2* kfo = (float2*)(ob + 4198400);             // 4,196,352 B
    unsigned short* Wb = (unsigned short*)(ob + 8394752);  // 262,144 B (ends 8.7MB)

    k0_convW<<<dim3(512), 256, 0, stream>>>(Wout, Wb);
    k1_kergen<<<dim3(256, 5), 256, 0, stream>>>(log_dt, wlr, wim, Pre, Pim, Bre, Bim, Cre, Cim, kF);
    k2_kernelfft<<<dim3(256), 256, 0, stream>>>(kF, kfo);
    k3_transpose<<<dim3(128, 64), dim3(32, 8), 0, stream>>>(x, u);
    k4_conv<<<dim3(2048), 256, 0, stream>>>(u, kfo, Dp, yg);
    k5_gemm_glu<<<dim3(32, 16), 256, 0, stream>>>(yg, Wb, bout);
    k6_ln<<<dim3(32, 16), 256, 0, stream>>>(yg, u, gamma, beta, (float*)d_out);
}

// Round 10
// 219.426 us; speedup vs baseline: 2.0892x; 1.2549x over previous
//
#include <hip/hip_runtime.h>

// S4 (SSSD) layer: L=2048, B=16, H=256, N2=32. Output f32.
// R10: k4 rewritten as register radix-16 FFT (16x16x16), twiddles in regs
// (2 sincos/FFT), 2 LDS transposes/FFT, fwd->inv register passthrough.
// k5+k6 fused into k56 (GEMM+GLU+residual+LN+store), saving 64MB traffic.

#define PI_F 3.14159265358979323846f
#define PI_D 3.14159265358979323846
#define LP(i) ((i) + ((i) >> 4))    // LDS pad for k2's fft_fused

typedef __attribute__((ext_vector_type(8))) short bf16x8;
typedef __attribute__((ext_vector_type(4))) float f32x4;

// ---------------- complex helpers ----------------
struct cd { double x, y; };
__device__ __forceinline__ cd cmuld(cd a, cd b) {
    return cd{a.x*b.x - a.y*b.y, a.x*b.y + a.y*b.x};
}
__device__ __forceinline__ cd cdivd(cd a, cd b) {
    double inv = 1.0 / (b.x*b.x + b.y*b.y);
    return cd{(a.x*b.x + a.y*b.y) * inv, (a.y*b.x - a.x*b.y) * inv};
}
__device__ __forceinline__ cd caccum(cd r, cd v, cd i1, cd i2) {
    r.x += v.x*i1.x - v.y*i1.y + v.x*i2.x + v.y*i2.y;
    r.y += v.x*i1.y + v.y*i1.x + v.x*i2.y - v.y*i2.x;
    return r;
}
__device__ __forceinline__ float2 cmulf(float2 a, float2 b) {
    return make_float2(a.x*b.x - a.y*b.y, a.x*b.y + a.y*b.x);
}
__device__ __forceinline__ unsigned short f2bf(float f) {
    unsigned int u = __float_as_uint(f);
    u += 0x7fffu + ((u >> 16) & 1u);
    return (unsigned short)(u >> 16);
}

// ---------------- 16-pt register FFT, compile-time twiddles -----------------
// Same butterfly structure as the verified fft_dit; all indices/twiddles fold.
template<int SGN>
__device__ __forceinline__ void fft16(float2 v[16]) {
    float2 tsw;
#define SW(i,j) { tsw = v[i]; v[i] = v[j]; v[j] = tsw; }
    SW(1,8) SW(2,4) SW(3,12) SW(5,10) SW(7,14) SW(11,13)
#undef SW
    const float C8[8] = {1.f, 0.92387953251f, 0.70710678119f, 0.38268343236f,
                         0.f, -0.38268343236f, -0.70710678119f, -0.92387953251f};
    const float S8[8] = {0.f, 0.38268343236f, 0.70710678119f, 0.92387953251f,
                         1.f, 0.92387953251f, 0.70710678119f, 0.38268343236f};
    #pragma unroll
    for (int s = 0; s < 4; ++s) {
        const int Ns = 1 << s;
        #pragma unroll
        for (int j = 0; j < 8; ++j) {
            const int k  = j & (Ns - 1);
            const int i0 = ((j >> s) << (s + 1)) | k;
            const int i1 = i0 + Ns;
            const int ti = k << (3 - s);
            const float cs = C8[ti];
            const float sn = (SGN < 0) ? -S8[ti] : S8[ti];
            float2 a = v[i0], b = v[i1];
            float2 t = make_float2(cs*b.x - sn*b.y, cs*b.y + sn*b.x);
            v[i0] = make_float2(a.x + t.x, a.y + t.y);
            v[i1] = make_float2(a.x - t.x, a.y - t.y);
        }
    }
}

// ------------- 4096-pt FFT: 3 phases of fft16, 2 LDS transposes -------------
// In: v[n1] = x[n1*256 + t].  Out: v[j2] = X[t + 256*j2].  lds: >=4366 float2.
template<int SGN>
__device__ __forceinline__ void fft4096p(float2 v[16], float2* lds, int t) {
    // Phase A (n1 -> k1) + twiddle W_4096^(t*k1)
    fft16<SGN>(v);
    float s1, c1;
    __sincosf((float)SGN * (2.0f * PI_F / 4096.0f) * (float)t, &s1, &c1);
    float2 w1 = make_float2(c1, s1), cur = make_float2(1.f, 0.f);
    #pragma unroll
    for (int k = 1; k < 16; ++k) { cur = cmulf(cur, w1); v[k] = cmulf(v[k], cur); }
    __syncthreads();                      // prior consumers of lds done
    #pragma unroll
    for (int k = 0; k < 16; ++k) lds[t * 17 + k] = v[k];   // LB[n2=t][k1]
    __syncthreads();
    // Phase B (m1 -> j1): thread -> (k1 = t&15, m2 = t>>4)
    const int k1 = t & 15, m2 = t >> 4;
    #pragma unroll
    for (int m1 = 0; m1 < 16; ++m1) v[m1] = lds[(m1 * 16 + m2) * 17 + k1];
    fft16<SGN>(v);
    float s2, c2;
    __sincosf((float)SGN * (2.0f * PI_F / 256.0f) * (float)m2, &s2, &c2);
    float2 w2 = make_float2(c2, s2); cur = make_float2(1.f, 0.f);
    #pragma unroll
    for (int j = 1; j < 16; ++j) { cur = cmulf(cur, w2); v[j] = cmulf(v[j], cur); }
    __syncthreads();                      // all LB reads done
    #pragma unroll
    for (int j = 0; j < 16; ++j) lds[m2 * 273 + j * 17 + k1] = v[j];  // LD[m2][j1][k1]
    __syncthreads();
    // Phase C (m2 -> j2): thread -> (k1 = t&15, j1 = t>>4)
    #pragma unroll
    for (int m = 0; m < 16; ++m) v[m] = lds[m * 273 + (t >> 4) * 17 + k1];
    fft16<SGN>(v);                        // v[j2] = X[k1 + 16*j1 + 256*j2] = X[t + 256*j2]
}

// -------- in-LDS fused double-stage FFT (kept for k2; verified) -------------
template<int SGN>
__device__ __forceinline__ void fft_fused(float2* A, int N, int logN,
                                          int tid, int nthr) {
    __syncthreads();
    for (int j = tid; j < N; j += nthr) {
        int r = (int)(__brev((unsigned)j) >> (32 - logN));
        if (r > j) { float2 t = A[LP(j)]; A[LP(j)] = A[LP(r)]; A[LP(r)] = t; }
    }
    __syncthreads();
    int s = 0;
    if (logN & 1) {
        for (int j = tid; j < (N >> 1); j += nthr) {
            int i0 = 2 * j;
            float2 a = A[LP(i0)], b = A[LP(i0 + 1)];
            A[LP(i0)]     = make_float2(a.x + b.x, a.y + b.y);
            A[LP(i0 + 1)] = make_float2(a.x - b.x, a.y - b.y);
        }
        __syncthreads();
        s = 1;
    }
    for (; s < logN; s += 2) {
        const int Ns = 1 << s;
        for (int g = tid; g < (N >> 2); g += nthr) {
            int k = g & (Ns - 1);
            int base = ((g >> s) << (s + 2)) | k;
            float2 a0 = A[LP(base)];
            float2 a1 = A[LP(base + Ns)];
            float2 a2 = A[LP(base + 2*Ns)];
            float2 a3 = A[LP(base + 3*Ns)];
            float ang1 = (float)SGN * PI_F * (float)k / (float)Ns;
            float sn1, cs1; __sincosf(ang1, &sn1, &cs1);
            float2 t = make_float2(cs1*a1.x - sn1*a1.y, cs1*a1.y + sn1*a1.x);
            float2 b0 = make_float2(a0.x + t.x, a0.y + t.y);
            float2 b1 = make_float2(a0.x - t.x, a0.y - t.y);
            t = make_float2(cs1*a3.x - sn1*a3.y, cs1*a3.y + sn1*a3.x);
            float2 b2 = make_float2(a2.x + t.x, a2.y + t.y);
            float2 b3 = make_float2(a2.x - t.x, a2.y - t.y);
            float ang2 = (float)SGN * PI_F * (float)k / (float)(2 * Ns);
            float sn2, cs2; __sincosf(ang2, &sn2, &cs2);
            t = make_float2(cs2*b2.x - sn2*b2.y, cs2*b2.y + sn2*b2.x);
            A[LP(base)]        = make_float2(b0.x + t.x, b0.y + t.y);
            A[LP(base + 2*Ns)] = make_float2(b0.x - t.x, b0.y - t.y);
            float c2p, s2p;
            if (SGN < 0) { c2p = sn2; s2p = -cs2; } else { c2p = -sn2; s2p = cs2; }
            t = make_float2(c2p*b3.x - s2p*b3.y, c2p*b3.y + s2p*b3.x);
            A[LP(base + Ns)]   = make_float2(b1.x + t.x, b1.y + t.y);
            A[LP(base + 3*Ns)] = make_float2(b1.x - t.x, b1.y - t.y);
        }
        __syncthreads();
    }
}

// ---------------- K0: convert W [512][256] f32 -> bf16 (row-major) ----------
__global__ void k0_convW(const float* __restrict__ W, unsigned short* __restrict__ Wb)
{
    int i = blockIdx.x * 256 + threadIdx.x;
    if (i < 512 * 256) Wb[i] = f2bf(W[i]);
}

// ---------------- K1: NPLR kernel generation (f64) ----------------
__global__ void k1_kergen(const float* __restrict__ log_dt, const float* __restrict__ wlr,
                          const float* __restrict__ wim, const float* __restrict__ Pre,
                          const float* __restrict__ Pim, const float* __restrict__ Bre,
                          const float* __restrict__ Bim, const float* __restrict__ Cre,
                          const float* __restrict__ Cim, float2* __restrict__ kf_out)
{
    int h = blockIdx.x;
    int f = blockIdx.y * 256 + threadIdx.x;
    if (f > 1024) return;
    double dt = exp((double)log_dt[h]);
    double th = -2.0 * PI_D * (double)f / 2048.0;
    double ox = cos(th), oy = sin(th);
    cd onep{1.0 + ox, oy};
    cd z = cdivd(cd{2.0*(1.0 - ox), -2.0*oy}, onep);
    cd r00{0,0}, r01{0,0}, r02{0,0}, r10{0,0}, r11{0,0}, r12{0,0};
    const int base = h * 32;
    for (int n = 0; n < 32; ++n) {
        double wre = -exp((double)wlr[base+n]) * dt;
        double wi  = (double)wim[base+n] * dt;
        cd i1 = cdivd(cd{1.0, 0.0}, cd{z.x - wre, z.y - wi});
        cd i2 = cdivd(cd{1.0, 0.0}, cd{z.x - wre, z.y + wi});
        cd B0{(double)Bre[base+n], (double)Bim[base+n]};
        cd P0{(double)Pre[base+n], (double)Pim[base+n]};
        cd C0{(double)Cre[base+n], (double)Cim[base+n]};
        cd C1{(double)Cre[8192+base+n], (double)Cim[8192+base+n]};
        cd C2{P0.x, -P0.y};
        r00 = caccum(r00, cmuld(B0, C0), i1, i2);
        r01 = caccum(r01, cmuld(B0, C1), i1, i2);
        r02 = caccum(r02, cmuld(B0, C2), i1, i2);
        r10 = caccum(r10, cmuld(P0, C0), i1, i2);
        r11 = caccum(r11, cmuld(P0, C1), i1, i2);
        r12 = caccum(r12, cmuld(P0, C2), i1, i2);
    }
    r00.x *= dt; r00.y *= dt; r01.x *= dt; r01.y *= dt; r02.x *= dt; r02.y *= dt;
    r10.x *= dt; r10.y *= dt; r11.x *= dt; r11.y *= dt; r12.x *= dt; r12.y *= dt;
    cd den{1.0 + r12.x, r12.y};
    cd fac = cdivd(cd{2.0, 0.0}, onep);
    cd t0 = cdivd(cmuld(r02, r10), den);
    cd k0{r00.x - t0.x, r00.y - t0.y};
    k0 = cmuld(k0, fac);
    cd t1 = cdivd(cmuld(r02, r11), den);
    cd k1{r01.x - t1.x, r01.y - t1.y};
    k1 = cmuld(k1, fac);
    kf_out[(size_t)h * 1025 + f]         = make_float2((float)k0.x, (float)k0.y);
    kf_out[(size_t)(256 + h) * 1025 + f] = make_float2((float)k1.x, (float)k1.y);
}

// ---------------- K2: packed irfft(ch0,ch1) -> kk -> fft4096 -> kf ----------
__global__ __launch_bounds__(256) void k2_kernelfft(const float2* __restrict__ kfin,
                                                    float2* __restrict__ kfout)
{
    __shared__ float2 A2[2176];
    __shared__ float2 A4[4352];
    int h = blockIdx.x, tid = threadIdx.x;
    const float2* s0 = kfin + (size_t)h * 1025;
    const float2* s1 = kfin + (size_t)(256 + h) * 1025;
    for (int j = tid; j < 2048; j += 256) {
        float2 q0, q1;
        if (j == 0)          { q0 = s0[0];    q0.y = 0.0f; q1 = s1[0];    q1.y = 0.0f; }
        else if (j < 1024)   { q0 = s0[j];                 q1 = s1[j]; }
        else if (j == 1024)  { q0 = s0[1024]; q0.y = 0.0f; q1 = s1[1024]; q1.y = 0.0f; }
        else { float2 t0 = s0[2048 - j], t1 = s1[2048 - j];
               q0 = make_float2(t0.x, -t0.y); q1 = make_float2(t1.x, -t1.y); }
        A2[LP(j)] = make_float2(q0.x - q1.y, q0.y + q1.x);   // E0 + i*E1
    }
    fft_fused<+1>(A2, 2048, 11, tid, 256);
    const float scl = 1.0f / 2048.0f;
    for (int j = tid; j < 2048; j += 256) {
        float2 v = A2[LP(j)];
        A4[LP(j)]        = make_float2(v.x * scl, 0.0f);
        A4[LP(4095 - j)] = make_float2(v.y * scl, 0.0f);
    }
    fft_fused<-1>(A4, 4096, 12, tid, 256);
    for (int F = tid; F <= 2048; F += 256)
        kfout[(size_t)h * 2049 + F] = A4[LP(F)];
}

// ---------------- K3: transpose x (2048 x 4096) -> u (4096 x 2048) ----------
__global__ void k3_transpose(const float* __restrict__ x, float* __restrict__ u)
{
    __shared__ float tile[32][33];
    int p0 = blockIdx.x * 32;
    int l0 = blockIdx.y * 32;
    int tx = threadIdx.x, ty = threadIdx.y;
    for (int i = ty; i < 32; i += 8)
        tile[i][tx] = x[(size_t)(l0 + i) * 4096 + p0 + tx];
    __syncthreads();
    for (int i = ty; i < 32; i += 8)
        u[(size_t)(p0 + i) * 2048 + l0 + tx] = tile[tx][i];
}

// ---------------- K4: pair-packed conv via register radix-16 FFT ------------
__global__ __launch_bounds__(256) void k4_conv(const float* __restrict__ u,
        const float2* __restrict__ kf, const float* __restrict__ Dp, float* __restrict__ yg)
{
    __shared__ float2 lds[4366];   // 34.9KB
    int h  = blockIdx.x & 255;
    int bp = blockIdx.x >> 8;
    int t  = threadIdx.x;
    const float* u0 = u + (size_t)((2*bp)   * 256 + h) * 2048;
    const float* u1 = u + (size_t)((2*bp+1) * 256 + h) * 2048;
    float2 v[16], us[8];
    #pragma unroll
    for (int n1 = 0; n1 < 8; ++n1) {
        int j = n1 * 256 + t;
        us[n1] = make_float2(u0[j], u1[j]);
        v[n1] = us[n1];
        v[n1 + 8] = make_float2(0.f, 0.f);
    }
    fft4096p<-1>(v, lds, t);
    const float2* kfh = kf + (size_t)h * 2049;
    #pragma unroll
    for (int j2 = 0; j2 < 16; ++j2) {
        int f = t + 256 * j2;
        float2 K;
        if (f <= 2048) K = kfh[f];
        else { float2 q = kfh[4096 - f]; K = make_float2(q.x, -q.y); }
        v[j2] = cmulf(v[j2], K);
    }
    fft4096p<+1>(v, lds, t);
    float d = Dp[h];
    float* o0 = yg + (size_t)((2*bp)   * 256 + h) * 2048;
    float* o1 = yg + (size_t)((2*bp+1) * 256 + h) * 2048;
    const float iscl = 1.0f / 4096.0f;
    #pragma unroll
    for (int j2 = 0; j2 < 8; ++j2) {
        int l = t + 256 * j2;
        float y0 = v[j2].x * iscl + d * us[j2].x;
        float y1 = v[j2].y * iscl + d * us[j2].y;
        o0[l] = 0.5f * y0 * (1.0f + erff(y0 * 0.70710678118654752f));
        o1[l] = 0.5f * y1 * (1.0f + erff(y1 * 0.70710678118654752f));
    }
}

// ---------------- K56: MFMA GEMM + GLU + residual + LayerNorm + store -------
// grid (32 l-tiles of 64, 16 b). Wave w owns l = l0+16w+cc; thread holds all
// 256 h across its gg-quad (64 each); LN reduce via shfl_xor(16/32).
__global__ __launch_bounds__(256, 2) void k56_gemm_glu_ln(const float* __restrict__ yg,
        const unsigned short* __restrict__ Wb, const float* __restrict__ bout,
        const float* __restrict__ u, const float* __restrict__ gamma,
        const float* __restrict__ beta, float* __restrict__ out)
{
    __shared__ short yt[64][264];
    __shared__ float bo[512];
    __shared__ float gb2[512];
    int b  = blockIdx.y;
    int l0 = blockIdx.x * 64;
    int tid = threadIdx.x;
    int lane = tid & 63, w = tid >> 6;
    int cc = lane & 15, gg = lane >> 4;
    bo[tid] = bout[tid]; bo[tid + 256] = bout[tid + 256];
    gb2[tid] = gamma[tid]; gb2[tid + 256] = beta[tid];
    int li = tid & 63;
    #pragma unroll 4
    for (int it = 0; it < 64; ++it) {
        int hh = (tid >> 6) + it * 4;
        float vv = yg[(size_t)(b * 256 + hh) * 2048 + l0 + li];
        yt[li][hh] = (short)f2bf(vv);
    }
    __syncthreads();
    f32x4 acc[32];
    #pragma unroll
    for (int tt = 0; tt < 32; ++tt) acc[tt] = (f32x4){0.f, 0.f, 0.f, 0.f};
    const short* brow = &yt[16 * w + cc][0];
    #pragma unroll
    for (int ks = 0; ks < 8; ++ks) {
        bf16x8 bfrag = *(const bf16x8*)(brow + ks * 32 + gg * 8);
        const unsigned short* wp = Wb + (size_t)cc * 256 + ks * 32 + gg * 8;
        #pragma unroll
        for (int tt = 0; tt < 32; ++tt) {
            bf16x8 afrag = *(const bf16x8*)(wp + (size_t)tt * 16 * 256);
            acc[tt] = __builtin_amdgcn_mfma_f32_16x16x32_bf16(afrag, bfrag, acc[tt], 0, 0, 0);
        }
    }
    // epilogue: GLU + residual; accumulate LN stats; reuse acc[0..15] storage
    int l = l0 + 16 * w + cc;
    const float* up = u + (size_t)b * 256 * 2048 + l;
    float s = 0.f, q2 = 0.f;
    #pragma unroll
    for (int tt = 0; tt < 16; ++tt) {
        #pragma unroll
        for (int r = 0; r < 4; ++r) {
            int P = tt * 16 + gg * 4 + r;
            float ya = acc[tt][r] + bo[P];
            float gb = acc[tt + 16][r] + bo[256 + P];
            float gv = ya / (1.0f + expf(-gb));
            float val = gv + up[(size_t)P * 2048];
            acc[tt][r] = val;
            s += val; q2 += val * val;
        }
    }
    s  += __shfl_xor(s, 16);  s  += __shfl_xor(s, 32);
    q2 += __shfl_xor(q2, 16); q2 += __shfl_xor(q2, 32);
    float mu = s * (1.0f / 256.0f);
    float var = q2 * (1.0f / 256.0f) - mu * mu;
    float rstd = rsqrtf(var + 1e-5f);
    float* ob = out + (size_t)(l * 16 + b) * 256;
    #pragma unroll
    for (int tt = 0; tt < 16; ++tt) {
        int P0 = tt * 16 + gg * 4;
        float4 o4;
        o4.x = (acc[tt][0] - mu) * rstd * gb2[P0 + 0] + gb2[256 + P0 + 0];
        o4.y = (acc[tt][1] - mu) * rstd * gb2[P0 + 1] + gb2[256 + P0 + 1];
        o4.z = (acc[tt][2] - mu) * rstd * gb2[P0 + 2] + gb2[256 + P0 + 2];
        o4.w = (acc[tt][3] - mu) * rstd * gb2[P0 + 3] + gb2[256 + P0 + 3];
        *(float4*)(ob + P0) = o4;
    }
}

// ---------------- launch ----------------
extern "C" void kernel_launch(void* const* d_in, const int* in_sizes, int n_in,
                              void* d_out, int out_size, void* d_ws, size_t ws_size,
                              hipStream_t stream)
{
    (void)in_sizes; (void)n_in; (void)out_size; (void)ws_size;
    const float* x      = (const float*)d_in[0];
    const float* log_dt = (const float*)d_in[1];
    const float* wlr    = (const float*)d_in[2];
    const float* wim    = (const float*)d_in[3];
    const float* Pre    = (const float*)d_in[4];
    const float* Pim    = (const float*)d_in[5];
    const float* Bre    = (const float*)d_in[6];
    const float* Bim    = (const float*)d_in[7];
    const float* Cre    = (const float*)d_in[8];
    const float* Cim    = (const float*)d_in[9];
    const float* Dp     = (const float*)d_in[10];
    const float* Wout   = (const float*)d_in[11];
    const float* bout   = (const float*)d_in[12];
    const float* gamma  = (const float*)d_in[13];
    const float* beta   = (const float*)d_in[14];

    float* ws  = (float*)d_ws;
    float* u   = ws;                 // 32MB (B,H,L)
    float* yg  = ws + 8388608;       // 32MB (B,H,L)
    char*  ob  = (char*)d_out;
    float2* kF  = (float2*)(ob);                       // 4,198,400 B
    float2* kfo = (float2*)(ob + 4198400);             // 4,196,352 B
    unsigned short* Wb = (unsigned short*)(ob + 8394752);  // 262,144 B

    k0_convW<<<dim3(512), 256, 0, stream>>>(Wout, Wb);
    k1_kergen<<<dim3(256, 5), 256, 0, stream>>>(log_dt, wlr, wim, Pre, Pim, Bre, Bim, Cre, Cim, kF);
    k2_kernelfft<<<dim3(256), 256, 0, stream>>>(kF, kfo);
    k3_transpose<<<dim3(128, 64), dim3(32, 8), 0, stream>>>(x, u);
    k4_conv<<<dim3(2048), 256, 0, stream>>>(u, kfo, Dp, yg);
    k56_gemm_glu_ln<<<dim3(32, 16), 256, 0, stream>>>(yg, Wb, bout, u, gamma, beta, (float*)d_out);
}

// Round 11
// 168.526 us; speedup vs baseline: 2.7202x; 1.3020x over previous
//
#include <hip/hip_runtime.h>

// S4 (SSSD) layer: L=2048, B=16, H=256, N2=32. Output f32.
// R11: k56's A-fragments (W) now come from LDS-staged 64-row chunks with
// register prefetch (async-stage split), instead of 256 per-wave scattered
// L2 loads. B-fragments preloaded once. Rest identical to R10.

#define PI_F 3.14159265358979323846f
#define PI_D 3.14159265358979323846
#define LP(i) ((i) + ((i) >> 4))    // LDS pad for k2's fft_fused

typedef __attribute__((ext_vector_type(8))) short bf16x8;
typedef __attribute__((ext_vector_type(4))) float f32x4;

// ---------------- complex helpers ----------------
struct cd { double x, y; };
__device__ __forceinline__ cd cmuld(cd a, cd b) {
    return cd{a.x*b.x - a.y*b.y, a.x*b.y + a.y*b.x};
}
__device__ __forceinline__ cd cdivd(cd a, cd b) {
    double inv = 1.0 / (b.x*b.x + b.y*b.y);
    return cd{(a.x*b.x + a.y*b.y) * inv, (a.y*b.x - a.x*b.y) * inv};
}
__device__ __forceinline__ cd caccum(cd r, cd v, cd i1, cd i2) {
    r.x += v.x*i1.x - v.y*i1.y + v.x*i2.x + v.y*i2.y;
    r.y += v.x*i1.y + v.y*i1.x + v.x*i2.y - v.y*i2.x;
    return r;
}
__device__ __forceinline__ float2 cmulf(float2 a, float2 b) {
    return make_float2(a.x*b.x - a.y*b.y, a.x*b.y + a.y*b.x);
}
__device__ __forceinline__ unsigned short f2bf(float f) {
    unsigned int u = __float_as_uint(f);
    u += 0x7fffu + ((u >> 16) & 1u);
    return (unsigned short)(u >> 16);
}

// ---------------- 16-pt register FFT, compile-time twiddles -----------------
template<int SGN>
__device__ __forceinline__ void fft16(float2 v[16]) {
    float2 tsw;
#define SW(i,j) { tsw = v[i]; v[i] = v[j]; v[j] = tsw; }
    SW(1,8) SW(2,4) SW(3,12) SW(5,10) SW(7,14) SW(11,13)
#undef SW
    const float C8[8] = {1.f, 0.92387953251f, 0.70710678119f, 0.38268343236f,
                         0.f, -0.38268343236f, -0.70710678119f, -0.92387953251f};
    const float S8[8] = {0.f, 0.38268343236f, 0.70710678119f, 0.92387953251f,
                         1.f, 0.92387953251f, 0.70710678119f, 0.38268343236f};
    #pragma unroll
    for (int s = 0; s < 4; ++s) {
        const int Ns = 1 << s;
        #pragma unroll
        for (int j = 0; j < 8; ++j) {
            const int k  = j & (Ns - 1);
            const int i0 = ((j >> s) << (s + 1)) | k;
            const int i1 = i0 + Ns;
            const int ti = k << (3 - s);
            const float cs = C8[ti];
            const float sn = (SGN < 0) ? -S8[ti] : S8[ti];
            float2 a = v[i0], b = v[i1];
            float2 t = make_float2(cs*b.x - sn*b.y, cs*b.y + sn*b.x);
            v[i0] = make_float2(a.x + t.x, a.y + t.y);
            v[i1] = make_float2(a.x - t.x, a.y - t.y);
        }
    }
}

// ------------- 4096-pt FFT: 3 phases of fft16, 2 LDS transposes -------------
template<int SGN>
__device__ __forceinline__ void fft4096p(float2 v[16], float2* lds, int t) {
    fft16<SGN>(v);
    float s1, c1;
    __sincosf((float)SGN * (2.0f * PI_F / 4096.0f) * (float)t, &s1, &c1);
    float2 w1 = make_float2(c1, s1), cur = make_float2(1.f, 0.f);
    #pragma unroll
    for (int k = 1; k < 16; ++k) { cur = cmulf(cur, w1); v[k] = cmulf(v[k], cur); }
    __syncthreads();
    #pragma unroll
    for (int k = 0; k < 16; ++k) lds[t * 17 + k] = v[k];
    __syncthreads();
    const int k1 = t & 15, m2 = t >> 4;
    #pragma unroll
    for (int m1 = 0; m1 < 16; ++m1) v[m1] = lds[(m1 * 16 + m2) * 17 + k1];
    fft16<SGN>(v);
    float s2, c2;
    __sincosf((float)SGN * (2.0f * PI_F / 256.0f) * (float)m2, &s2, &c2);
    float2 w2 = make_float2(c2, s2); cur = make_float2(1.f, 0.f);
    #pragma unroll
    for (int j = 1; j < 16; ++j) { cur = cmulf(cur, w2); v[j] = cmulf(v[j], cur); }
    __syncthreads();
    #pragma unroll
    for (int j = 0; j < 16; ++j) lds[m2 * 273 + j * 17 + k1] = v[j];
    __syncthreads();
    #pragma unroll
    for (int m = 0; m < 16; ++m) v[m] = lds[m * 273 + (t >> 4) * 17 + k1];
    fft16<SGN>(v);
}

// -------- in-LDS fused double-stage FFT (kept for k2; verified) -------------
template<int SGN>
__device__ __forceinline__ void fft_fused(float2* A, int N, int logN,
                                          int tid, int nthr) {
    __syncthreads();
    for (int j = tid; j < N; j += nthr) {
        int r = (int)(__brev((unsigned)j) >> (32 - logN));
        if (r > j) { float2 t = A[LP(j)]; A[LP(j)] = A[LP(r)]; A[LP(r)] = t; }
    }
    __syncthreads();
    int s = 0;
    if (logN & 1) {
        for (int j = tid; j < (N >> 1); j += nthr) {
            int i0 = 2 * j;
            float2 a = A[LP(i0)], b = A[LP(i0 + 1)];
            A[LP(i0)]     = make_float2(a.x + b.x, a.y + b.y);
            A[LP(i0 + 1)] = make_float2(a.x - b.x, a.y - b.y);
        }
        __syncthreads();
        s = 1;
    }
    for (; s < logN; s += 2) {
        const int Ns = 1 << s;
        for (int g = tid; g < (N >> 2); g += nthr) {
            int k = g & (Ns - 1);
            int base = ((g >> s) << (s + 2)) | k;
            float2 a0 = A[LP(base)];
            float2 a1 = A[LP(base + Ns)];
            float2 a2 = A[LP(base + 2*Ns)];
            float2 a3 = A[LP(base + 3*Ns)];
            float ang1 = (float)SGN * PI_F * (float)k / (float)Ns;
            float sn1, cs1; __sincosf(ang1, &sn1, &cs1);
            float2 t = make_float2(cs1*a1.x - sn1*a1.y, cs1*a1.y + sn1*a1.x);
            float2 b0 = make_float2(a0.x + t.x, a0.y + t.y);
            float2 b1 = make_float2(a0.x - t.x, a0.y - t.y);
            t = make_float2(cs1*a3.x - sn1*a3.y, cs1*a3.y + sn1*a3.x);
            float2 b2 = make_float2(a2.x + t.x, a2.y + t.y);
            float2 b3 = make_float2(a2.x - t.x, a2.y - t.y);
            float ang2 = (float)SGN * PI_F * (float)k / (float)(2 * Ns);
            float sn2, cs2; __sincosf(ang2, &sn2, &cs2);
            t = make_float2(cs2*b2.x - sn2*b2.y, cs2*b2.y + sn2*b2.x);
            A[LP(base)]        = make_float2(b0.x + t.x, b0.y + t.y);
            A[LP(base + 2*Ns)] = make_float2(b0.x - t.x, b0.y - t.y);
            float c2p, s2p;
            if (SGN < 0) { c2p = sn2; s2p = -cs2; } else { c2p = -sn2; s2p = cs2; }
            t = make_float2(c2p*b3.x - s2p*b3.y, c2p*b3.y + s2p*b3.x);
            A[LP(base + Ns)]   = make_float2(b1.x + t.x, b1.y + t.y);
            A[LP(base + 3*Ns)] = make_float2(b1.x - t.x, b1.y - t.y);
        }
        __syncthreads();
    }
}

// ---------------- K0: convert W [512][256] f32 -> bf16 (row-major) ----------
__global__ void k0_convW(const float* __restrict__ W, unsigned short* __restrict__ Wb)
{
    int i = blockIdx.x * 256 + threadIdx.x;
    if (i < 512 * 256) Wb[i] = f2bf(W[i]);
}

// ---------------- K1: NPLR kernel generation (f64) ----------------
__global__ void k1_kergen(const float* __restrict__ log_dt, const float* __restrict__ wlr,
                          const float* __restrict__ wim, const float* __restrict__ Pre,
                          const float* __restrict__ Pim, const float* __restrict__ Bre,
                          const float* __restrict__ Bim, const float* __restrict__ Cre,
                          const float* __restrict__ Cim, float2* __restrict__ kf_out)
{
    int h = blockIdx.x;
    int f = blockIdx.y * 256 + threadIdx.x;
    if (f > 1024) return;
    double dt = exp((double)log_dt[h]);
    double th = -2.0 * PI_D * (double)f / 2048.0;
    double ox = cos(th), oy = sin(th);
    cd onep{1.0 + ox, oy};
    cd z = cdivd(cd{2.0*(1.0 - ox), -2.0*oy}, onep);
    cd r00{0,0}, r01{0,0}, r02{0,0}, r10{0,0}, r11{0,0}, r12{0,0};
    const int base = h * 32;
    for (int n = 0; n < 32; ++n) {
        double wre = -exp((double)wlr[base+n]) * dt;
        double wi  = (double)wim[base+n] * dt;
        cd i1 = cdivd(cd{1.0, 0.0}, cd{z.x - wre, z.y - wi});
        cd i2 = cdivd(cd{1.0, 0.0}, cd{z.x - wre, z.y + wi});
        cd B0{(double)Bre[base+n], (double)Bim[base+n]};
        cd P0{(double)Pre[base+n], (double)Pim[base+n]};
        cd C0{(double)Cre[base+n], (double)Cim[base+n]};
        cd C1{(double)Cre[8192+base+n], (double)Cim[8192+base+n]};
        cd C2{P0.x, -P0.y};
        r00 = caccum(r00, cmuld(B0, C0), i1, i2);
        r01 = caccum(r01, cmuld(B0, C1), i1, i2);
        r02 = caccum(r02, cmuld(B0, C2), i1, i2);
        r10 = caccum(r10, cmuld(P0, C0), i1, i2);
        r11 = caccum(r11, cmuld(P0, C1), i1, i2);
        r12 = caccum(r12, cmuld(P0, C2), i1, i2);
    }
    r00.x *= dt; r00.y *= dt; r01.x *= dt; r01.y *= dt; r02.x *= dt; r02.y *= dt;
    r10.x *= dt; r10.y *= dt; r11.x *= dt; r11.y *= dt; r12.x *= dt; r12.y *= dt;
    cd den{1.0 + r12.x, r12.y};
    cd fac = cdivd(cd{2.0, 0.0}, onep);
    cd t0 = cdivd(cmuld(r02, r10), den);
    cd k0{r00.x - t0.x, r00.y - t0.y};
    k0 = cmuld(k0, fac);
    cd t1 = cdivd(cmuld(r02, r11), den);
    cd k1{r01.x - t1.x, r01.y - t1.y};
    k1 = cmuld(k1, fac);
    kf_out[(size_t)h * 1025 + f]         = make_float2((float)k0.x, (float)k0.y);
    kf_out[(size_t)(256 + h) * 1025 + f] = make_float2((float)k1.x, (float)k1.y);
}

// ---------------- K2: packed irfft(ch0,ch1) -> kk -> fft4096 -> kf ----------
__global__ __launch_bounds__(256) void k2_kernelfft(const float2* __restrict__ kfin,
                                                    float2* __restrict__ kfout)
{
    __shared__ float2 A2[2176];
    __shared__ float2 A4[4352];
    int h = blockIdx.x, tid = threadIdx.x;
    const float2* s0 = kfin + (size_t)h * 1025;
    const float2* s1 = kfin + (size_t)(256 + h) * 1025;
    for (int j = tid; j < 2048; j += 256) {
        float2 q0, q1;
        if (j == 0)          { q0 = s0[0];    q0.y = 0.0f; q1 = s1[0];    q1.y = 0.0f; }
        else if (j < 1024)   { q0 = s0[j];                 q1 = s1[j]; }
        else if (j == 1024)  { q0 = s0[1024]; q0.y = 0.0f; q1 = s1[1024]; q1.y = 0.0f; }
        else { float2 t0 = s0[2048 - j], t1 = s1[2048 - j];
               q0 = make_float2(t0.x, -t0.y); q1 = make_float2(t1.x, -t1.y); }
        A2[LP(j)] = make_float2(q0.x - q1.y, q0.y + q1.x);   // E0 + i*E1
    }
    fft_fused<+1>(A2, 2048, 11, tid, 256);
    const float scl = 1.0f / 2048.0f;
    for (int j = tid; j < 2048; j += 256) {
        float2 v = A2[LP(j)];
        A4[LP(j)]        = make_float2(v.x * scl, 0.0f);
        A4[LP(4095 - j)] = make_float2(v.y * scl, 0.0f);
    }
    fft_fused<-1>(A4, 4096, 12, tid, 256);
    for (int F = tid; F <= 2048; F += 256)
        kfout[(size_t)h * 2049 + F] = A4[LP(F)];
}

// ---------------- K3: transpose x (2048 x 4096) -> u (4096 x 2048) ----------
__global__ void k3_transpose(const float* __restrict__ x, float* __restrict__ u)
{
    __shared__ float tile[32][33];
    int p0 = blockIdx.x * 32;
    int l0 = blockIdx.y * 32;
    int tx = threadIdx.x, ty = threadIdx.y;
    for (int i = ty; i < 32; i += 8)
        tile[i][tx] = x[(size_t)(l0 + i) * 4096 + p0 + tx];
    __syncthreads();
    for (int i = ty; i < 32; i += 8)
        u[(size_t)(p0 + i) * 2048 + l0 + tx] = tile[tx][i];
}

// ---------------- K4: pair-packed conv via register radix-16 FFT ------------
__global__ __launch_bounds__(256) void k4_conv(const float* __restrict__ u,
        const float2* __restrict__ kf, const float* __restrict__ Dp, float* __restrict__ yg)
{
    __shared__ float2 lds[4366];
    int h  = blockIdx.x & 255;
    int bp = blockIdx.x >> 8;
    int t  = threadIdx.x;
    const float* u0 = u + (size_t)((2*bp)   * 256 + h) * 2048;
    const float* u1 = u + (size_t)((2*bp+1) * 256 + h) * 2048;
    float2 v[16], us[8];
    #pragma unroll
    for (int n1 = 0; n1 < 8; ++n1) {
        int j = n1 * 256 + t;
        us[n1] = make_float2(u0[j], u1[j]);
        v[n1] = us[n1];
        v[n1 + 8] = make_float2(0.f, 0.f);
    }
    fft4096p<-1>(v, lds, t);
    const float2* kfh = kf + (size_t)h * 2049;
    #pragma unroll
    for (int j2 = 0; j2 < 16; ++j2) {
        int f = t + 256 * j2;
        float2 K;
        if (f <= 2048) K = kfh[f];
        else { float2 q = kfh[4096 - f]; K = make_float2(q.x, -q.y); }
        v[j2] = cmulf(v[j2], K);
    }
    fft4096p<+1>(v, lds, t);
    float d = Dp[h];
    float* o0 = yg + (size_t)((2*bp)   * 256 + h) * 2048;
    float* o1 = yg + (size_t)((2*bp+1) * 256 + h) * 2048;
    const float iscl = 1.0f / 4096.0f;
    #pragma unroll
    for (int j2 = 0; j2 < 8; ++j2) {
        int l = t + 256 * j2;
        float y0 = v[j2].x * iscl + d * us[j2].x;
        float y1 = v[j2].y * iscl + d * us[j2].y;
        o0[l] = 0.5f * y0 * (1.0f + erff(y0 * 0.70710678118654752f));
        o1[l] = 0.5f * y1 * (1.0f + erff(y1 * 0.70710678118654752f));
    }
}

// ---------------- K56: MFMA GEMM + GLU + residual + LayerNorm + store -------
// grid (32 l-tiles of 64, 16 b). W staged to LDS in 64-row chunks with
// register prefetch; A-frags via ds_read_b128 (padded 264-short rows).
__global__ __launch_bounds__(256, 2) void k56_gemm_glu_ln(const float* __restrict__ yg,
        const unsigned short* __restrict__ Wb, const float* __restrict__ bout,
        const float* __restrict__ u, const float* __restrict__ gamma,
        const float* __restrict__ beta, float* __restrict__ out)
{
    __shared__ short yt[64][264];
    __shared__ short Wl[64][264];
    __shared__ float bo[512];
    __shared__ float gb2[512];
    int b  = blockIdx.y;
    int l0 = blockIdx.x * 64;
    int tid = threadIdx.x;
    int lane = tid & 63, w = tid >> 6;
    int cc = lane & 15, gg = lane >> 4;
    bo[tid] = bout[tid]; bo[tid + 256] = bout[tid + 256];
    gb2[tid] = gamma[tid]; gb2[tid + 256] = beta[tid];
    int li = tid & 63;
    #pragma unroll 4
    for (int it = 0; it < 64; ++it) {
        int hh = (tid >> 6) + it * 4;
        float vv = yg[(size_t)(b * 256 + hh) * 2048 + l0 + li];
        yt[li][hh] = (short)f2bf(vv);
    }
    __syncthreads();
    // preload B-fragments (chunk-invariant)
    const short* brow = &yt[16 * w + cc][0];
    bf16x8 bfr[8];
    #pragma unroll
    for (int ks = 0; ks < 8; ++ks) bfr[ks] = *(const bf16x8*)(brow + ks * 32 + gg * 8);
    f32x4 acc[32];
    #pragma unroll
    for (int tt = 0; tt < 32; ++tt) acc[tt] = (f32x4){0.f, 0.f, 0.f, 0.f};
    const int fr = tid >> 5, fch = tid & 31;    // staging row / 16B-chunk
    bf16x8 pre[8];
    #pragma unroll
    for (int j = 0; j < 8; ++j)
        pre[j] = *(const bf16x8*)(Wb + (size_t)(fr + j * 8) * 256 + fch * 8);
    #pragma unroll
    for (int c = 0; c < 8; ++c) {
        // Wl free: first iter after yt barrier; later iters after chunk barrier
        #pragma unroll
        for (int j = 0; j < 8; ++j)
            *(bf16x8*)&Wl[fr + j * 8][fch * 8] = pre[j];
        __syncthreads();
        if (c < 7) {
            #pragma unroll
            for (int j = 0; j < 8; ++j)
                pre[j] = *(const bf16x8*)(Wb + (size_t)((c + 1) * 64 + fr + j * 8) * 256 + fch * 8);
        }
        #pragma unroll
        for (int ks = 0; ks < 8; ++ks) {
            #pragma unroll
            for (int tl = 0; tl < 4; ++tl) {
                bf16x8 afrag = *(const bf16x8*)&Wl[tl * 16 + cc][ks * 32 + gg * 8];
                acc[c * 4 + tl] = __builtin_amdgcn_mfma_f32_16x16x32_bf16(
                    afrag, bfr[ks], acc[c * 4 + tl], 0, 0, 0);
            }
        }
        __syncthreads();   // all reads of Wl done before next overwrite
    }
    // epilogue: GLU + residual; LN stats; in-place into acc[0..15]
    int l = l0 + 16 * w + cc;
    const float* up = u + (size_t)b * 256 * 2048 + l;
    float s = 0.f, q2 = 0.f;
    #pragma unroll
    for (int tt = 0; tt < 16; ++tt) {
        #pragma unroll
        for (int r = 0; r < 4; ++r) {
            int P = tt * 16 + gg * 4 + r;
            float ya = acc[tt][r] + bo[P];
            float gb = acc[tt + 16][r] + bo[256 + P];
            float gv = ya / (1.0f + expf(-gb));
            float val = gv + up[(size_t)P * 2048];
            acc[tt][r] = val;
            s += val; q2 += val * val;
        }
    }
    s  += __shfl_xor(s, 16);  s  += __shfl_xor(s, 32);
    q2 += __shfl_xor(q2, 16); q2 += __shfl_xor(q2, 32);
    float mu = s * (1.0f / 256.0f);
    float var = q2 * (1.0f / 256.0f) - mu * mu;
    float rstd = rsqrtf(var + 1e-5f);
    float* ob = out + (size_t)(l * 16 + b) * 256;
    #pragma unroll
    for (int tt = 0; tt < 16; ++tt) {
        int P0 = tt * 16 + gg * 4;
        float4 o4;
        o4.x = (acc[tt][0] - mu) * rstd * gb2[P0 + 0] + gb2[256 + P0 + 0];
        o4.y = (acc[tt][1] - mu) * rstd * gb2[P0 + 1] + gb2[256 + P0 + 1];
        o4.z = (acc[tt][2] - mu) * rstd * gb2[P0 + 2] + gb2[256 + P0 + 2];
        o4.w = (acc[tt][3] - mu) * rstd * gb2[P0 + 3] + gb2[256 + P0 + 3];
        *(float4*)(ob + P0) = o4;
    }
}

// ---------------- launch ----------------
extern "C" void kernel_launch(void* const* d_in, const int* in_sizes, int n_in,
                              void* d_out, int out_size, void* d_ws, size_t ws_size,
                              hipStream_t stream)
{
    (void)in_sizes; (void)n_in; (void)out_size; (void)ws_size;
    const float* x      = (const float*)d_in[0];
    const float* log_dt = (const float*)d_in[1];
    const float* wlr    = (const float*)d_in[2];
    const float* wim    = (const float*)d_in[3];
    const float* Pre    = (const float*)d_in[4];
    const float* Pim    = (const float*)d_in[5];
    const float* Bre    = (const float*)d_in[6];
    const float* Bim    = (const float*)d_in[7];
    const float* Cre    = (const float*)d_in[8];
    const float* Cim    = (const float*)d_in[9];
    const float* Dp     = (const float*)d_in[10];
    const float* Wout   = (const float*)d_in[11];
    const float* bout   = (const float*)d_in[12];
    const float* gamma  = (const float*)d_in[13];
    const float* beta   = (const float*)d_in[14];

    float* ws  = (float*)d_ws;
    float* u   = ws;                 // 32MB (B,H,L)
    float* yg  = ws + 8388608;       // 32MB (B,H,L)
    char*  ob  = (char*)d_out;
    float2* kF  = (float2*)(ob);                       // 4,198,400 B
    float2* kfo = (float2*)(ob + 4198400);             // 4,196,352 B
    unsigned short* Wb = (unsigned short*)(ob + 8394752);  // 262,144 B

    k0_convW<<<dim3(512), 256, 0, stream>>>(Wout, Wb);
    k1_kergen<<<dim3(256, 5), 256, 0, stream>>>(log_dt, wlr, wim, Pre, Pim, Bre, Bim, Cre, Cim, kF);
    k2_kernelfft<<<dim3(256), 256, 0, stream>>>(kF, kfo);
    k3_transpose<<<dim3(128, 64), dim3(32, 8), 0, stream>>>(x, u);
    k4_conv<<<dim3(2048), 256, 0, stream>>>(u, kfo, Dp, yg);
    k56_gemm_glu_ln<<<dim3(32, 16), 256, 0, stream>>>(yg, Wb, bout, u, gamma, beta, (float*)d_out);
}

// Round 12
// 138.731 us; speedup vs baseline: 3.3044x; 1.2148x over previous
//
#include <hip/hip_runtime.h>

// S4 (SSSD) layer: L=2048, B=16, H=256, N2=32. Output f32.
// R12: k1 kergen rewritten in f32 (reference itself is complex64) with
// per-block LDS precompute of per-(h,n) constants (exp hoisted 1025x -> 1x,
// f64 software divides -> f32 reciprocals). Near-Nyquist cancellation is
// multiplicative, f32-safe. Rest identical to R11.

#define PI_F 3.14159265358979323846f
#define LP(i) ((i) + ((i) >> 4))    // LDS pad for k2's fft_fused

typedef __attribute__((ext_vector_type(8))) short bf16x8;
typedef __attribute__((ext_vector_type(4))) float f32x4;

__device__ __forceinline__ float2 cmulf(float2 a, float2 b) {
    return make_float2(a.x*b.x - a.y*b.y, a.x*b.y + a.y*b.x);
}
__device__ __forceinline__ unsigned short f2bf(float f) {
    unsigned int u = __float_as_uint(f);
    u += 0x7fffu + ((u >> 16) & 1u);
    return (unsigned short)(u >> 16);
}

// ---------------- 16-pt register FFT, compile-time twiddles -----------------
template<int SGN>
__device__ __forceinline__ void fft16(float2 v[16]) {
    float2 tsw;
#define SW(i,j) { tsw = v[i]; v[i] = v[j]; v[j] = tsw; }
    SW(1,8) SW(2,4) SW(3,12) SW(5,10) SW(7,14) SW(11,13)
#undef SW
    const float C8[8] = {1.f, 0.92387953251f, 0.70710678119f, 0.38268343236f,
                         0.f, -0.38268343236f, -0.70710678119f, -0.92387953251f};
    const float S8[8] = {0.f, 0.38268343236f, 0.70710678119f, 0.92387953251f,
                         1.f, 0.92387953251f, 0.70710678119f, 0.38268343236f};
    #pragma unroll
    for (int s = 0; s < 4; ++s) {
        const int Ns = 1 << s;
        #pragma unroll
        for (int j = 0; j < 8; ++j) {
            const int k  = j & (Ns - 1);
            const int i0 = ((j >> s) << (s + 1)) | k;
            const int i1 = i0 + Ns;
            const int ti = k << (3 - s);
            const float cs = C8[ti];
            const float sn = (SGN < 0) ? -S8[ti] : S8[ti];
            float2 a = v[i0], b = v[i1];
            float2 t = make_float2(cs*b.x - sn*b.y, cs*b.y + sn*b.x);
            v[i0] = make_float2(a.x + t.x, a.y + t.y);
            v[i1] = make_float2(a.x - t.x, a.y - t.y);
        }
    }
}

// ------------- 4096-pt FFT: 3 phases of fft16, 2 LDS transposes -------------
template<int SGN>
__device__ __forceinline__ void fft4096p(float2 v[16], float2* lds, int t) {
    fft16<SGN>(v);
    float s1, c1;
    __sincosf((float)SGN * (2.0f * PI_F / 4096.0f) * (float)t, &s1, &c1);
    float2 w1 = make_float2(c1, s1), cur = make_float2(1.f, 0.f);
    #pragma unroll
    for (int k = 1; k < 16; ++k) { cur = cmulf(cur, w1); v[k] = cmulf(v[k], cur); }
    __syncthreads();
    #pragma unroll
    for (int k = 0; k < 16; ++k) lds[t * 17 + k] = v[k];
    __syncthreads();
    const int k1 = t & 15, m2 = t >> 4;
    #pragma unroll
    for (int m1 = 0; m1 < 16; ++m1) v[m1] = lds[(m1 * 16 + m2) * 17 + k1];
    fft16<SGN>(v);
    float s2, c2;
    __sincosf((float)SGN * (2.0f * PI_F / 256.0f) * (float)m2, &s2, &c2);
    float2 w2 = make_float2(c2, s2); cur = make_float2(1.f, 0.f);
    #pragma unroll
    for (int j = 1; j < 16; ++j) { cur = cmulf(cur, w2); v[j] = cmulf(v[j], cur); }
    __syncthreads();
    #pragma unroll
    for (int j = 0; j < 16; ++j) lds[m2 * 273 + j * 17 + k1] = v[j];
    __syncthreads();
    #pragma unroll
    for (int m = 0; m < 16; ++m) v[m] = lds[m * 273 + (t >> 4) * 17 + k1];
    fft16<SGN>(v);
}

// -------- in-LDS fused double-stage FFT (kept for k2; verified) -------------
template<int SGN>
__device__ __forceinline__ void fft_fused(float2* A, int N, int logN,
                                          int tid, int nthr) {
    __syncthreads();
    for (int j = tid; j < N; j += nthr) {
        int r = (int)(__brev((unsigned)j) >> (32 - logN));
        if (r > j) { float2 t = A[LP(j)]; A[LP(j)] = A[LP(r)]; A[LP(r)] = t; }
    }
    __syncthreads();
    int s = 0;
    if (logN & 1) {
        for (int j = tid; j < (N >> 1); j += nthr) {
            int i0 = 2 * j;
            float2 a = A[LP(i0)], b = A[LP(i0 + 1)];
            A[LP(i0)]     = make_float2(a.x + b.x, a.y + b.y);
            A[LP(i0 + 1)] = make_float2(a.x - b.x, a.y - b.y);
        }
        __syncthreads();
        s = 1;
    }
    for (; s < logN; s += 2) {
        const int Ns = 1 << s;
        for (int g = tid; g < (N >> 2); g += nthr) {
            int k = g & (Ns - 1);
            int base = ((g >> s) << (s + 2)) | k;
            float2 a0 = A[LP(base)];
            float2 a1 = A[LP(base + Ns)];
            float2 a2 = A[LP(base + 2*Ns)];
            float2 a3 = A[LP(base + 3*Ns)];
            float ang1 = (float)SGN * PI_F * (float)k / (float)Ns;
            float sn1, cs1; __sincosf(ang1, &sn1, &cs1);
            float2 t = make_float2(cs1*a1.x - sn1*a1.y, cs1*a1.y + sn1*a1.x);
            float2 b0 = make_float2(a0.x + t.x, a0.y + t.y);
            float2 b1 = make_float2(a0.x - t.x, a0.y - t.y);
            t = make_float2(cs1*a3.x - sn1*a3.y, cs1*a3.y + sn1*a3.x);
            float2 b2 = make_float2(a2.x + t.x, a2.y + t.y);
            float2 b3 = make_float2(a2.x - t.x, a2.y - t.y);
            float ang2 = (float)SGN * PI_F * (float)k / (float)(2 * Ns);
            float sn2, cs2; __sincosf(ang2, &sn2, &cs2);
            t = make_float2(cs2*b2.x - sn2*b2.y, cs2*b2.y + sn2*b2.x);
            A[LP(base)]        = make_float2(b0.x + t.x, b0.y + t.y);
            A[LP(base + 2*Ns)] = make_float2(b0.x - t.x, b0.y - t.y);
            float c2p, s2p;
            if (SGN < 0) { c2p = sn2; s2p = -cs2; } else { c2p = -sn2; s2p = cs2; }
            t = make_float2(c2p*b3.x - s2p*b3.y, c2p*b3.y + s2p*b3.x);
            A[LP(base + Ns)]   = make_float2(b1.x + t.x, b1.y + t.y);
            A[LP(base + 3*Ns)] = make_float2(b1.x - t.x, b1.y - t.y);
        }
        __syncthreads();
    }
}

// ---------------- K0: convert W [512][256] f32 -> bf16 (row-major) ----------
__global__ void k0_convW(const float* __restrict__ W, unsigned short* __restrict__ Wb)
{
    int i = blockIdx.x * 256 + threadIdx.x;
    if (i < 512 * 256) Wb[i] = f2bf(W[i]);
}

// ---------------- K1: NPLR kernel generation (f32, LDS-hoisted) -------------
// grid (256, 5): block = one h, 256 f-values. Per-(h,n) constants in LDS.
__global__ __launch_bounds__(256) void k1_kergen(const float* __restrict__ log_dt,
                          const float* __restrict__ wlr, const float* __restrict__ wim,
                          const float* __restrict__ Pre, const float* __restrict__ Pim,
                          const float* __restrict__ Bre, const float* __restrict__ Bim,
                          const float* __restrict__ Cre, const float* __restrict__ Cim,
                          float2* __restrict__ kf_out)
{
    __shared__ float wreS[32], wiS[32];
    __shared__ float2 v00[32], v01[32], v02[32], v10[32], v11[32], v12[32];
    int h = blockIdx.x;
    int tid = threadIdx.x;
    float dt = expf(log_dt[h]);
    if (tid < 32) {
        int i = h * 32 + tid;
        wreS[tid] = -expf(wlr[i]) * dt;
        wiS[tid]  = wim[i] * dt;
        float2 B  = make_float2(Bre[i], Bim[i]);
        float2 P  = make_float2(Pre[i], Pim[i]);
        float2 C0 = make_float2(Cre[i], Cim[i]);
        float2 C1 = make_float2(Cre[8192 + i], Cim[8192 + i]);
        float2 Pc = make_float2(P.x, -P.y);
        v00[tid] = cmulf(B, C0); v01[tid] = cmulf(B, C1); v02[tid] = cmulf(B, Pc);
        v10[tid] = cmulf(P, C0); v11[tid] = cmulf(P, C1); v12[tid] = cmulf(P, Pc);
    }
    __syncthreads();
    int f = blockIdx.y * 256 + tid;
    if (f > 1024) return;
    float ang = -(2.0f * PI_F / 2048.0f) * (float)f;
    float sn, cs;
    sincosf(ang, &sn, &cs);
    float2 onep = make_float2(1.0f + cs, sn);
    float invo = 1.0f / (onep.x * onep.x + onep.y * onep.y);
    float2 oinv = make_float2(onep.x * invo, -onep.y * invo);     // 1/onep
    float2 z = cmulf(make_float2(2.0f * (1.0f - cs), -2.0f * sn), oinv);
    float2 r00 = {0,0}, r01 = {0,0}, r02 = {0,0};
    float2 r10 = {0,0}, r11 = {0,0}, r12 = {0,0};
    #pragma unroll 4
    for (int n = 0; n < 32; ++n) {
        float zx  = z.x - wreS[n];
        float d1y = z.y - wiS[n];
        float d2y = z.y + wiS[n];
        float inv1 = 1.0f / (zx * zx + d1y * d1y);
        float inv2 = 1.0f / (zx * zx + d2y * d2y);
        // i1 = (zx, -d1y)*inv1 ; i2 = (zx, -d2y)*inv2
        float sx = zx * (inv1 + inv2);          // i1.x + i2.x
        float dx = zx * (inv1 - inv2);          // i1.x - i2.x
        float sy = -(d1y * inv1 + d2y * inv2);  // i1.y + i2.y
        float dy = d1y * inv1 - d2y * inv2;     // i2.y - i1.y
        // r += v*i1 + conj(v)*i2  ->  r.x += v.x*sx + v.y*dy ; r.y += v.x*sy + v.y*dx
        float2 v;
        v = v00[n]; r00.x += v.x*sx + v.y*dy; r00.y += v.x*sy + v.y*dx;
        v = v01[n]; r01.x += v.x*sx + v.y*dy; r01.y += v.x*sy + v.y*dx;
        v = v02[n]; r02.x += v.x*sx + v.y*dy; r02.y += v.x*sy + v.y*dx;
        v = v10[n]; r10.x += v.x*sx + v.y*dy; r10.y += v.x*sy + v.y*dx;
        v = v11[n]; r11.x += v.x*sx + v.y*dy; r11.y += v.x*sy + v.y*dx;
        v = v12[n]; r12.x += v.x*sx + v.y*dy; r12.y += v.x*sy + v.y*dx;
    }
    // r *= dt; Woodbury; k = (r0j - r02*r1j/(1+r12)) * 2/onep
    r00.x *= dt; r00.y *= dt; r01.x *= dt; r01.y *= dt; r02.x *= dt; r02.y *= dt;
    r10.x *= dt; r10.y *= dt; r11.x *= dt; r11.y *= dt; r12.x *= dt; r12.y *= dt;
    float2 den = make_float2(1.0f + r12.x, r12.y);
    float invd = 1.0f / (den.x * den.x + den.y * den.y);
    float2 idn = make_float2(den.x * invd, -den.y * invd);
    float2 fac = make_float2(2.0f * oinv.x, 2.0f * oinv.y);
    float2 t0 = cmulf(cmulf(r02, r10), idn);
    float2 k0 = cmulf(make_float2(r00.x - t0.x, r00.y - t0.y), fac);
    float2 t1 = cmulf(cmulf(r02, r11), idn);
    float2 k1 = cmulf(make_float2(r01.x - t1.x, r01.y - t1.y), fac);
    kf_out[(size_t)h * 1025 + f]         = k0;
    kf_out[(size_t)(256 + h) * 1025 + f] = k1;
}

// ---------------- K2: packed irfft(ch0,ch1) -> kk -> fft4096 -> kf ----------
__global__ __launch_bounds__(256) void k2_kernelfft(const float2* __restrict__ kfin,
                                                    float2* __restrict__ kfout)
{
    __shared__ float2 A2[2176];
    __shared__ float2 A4[4352];
    int h = blockIdx.x, tid = threadIdx.x;
    const float2* s0 = kfin + (size_t)h * 1025;
    const float2* s1 = kfin + (size_t)(256 + h) * 1025;
    for (int j = tid; j < 2048; j += 256) {
        float2 q0, q1;
        if (j == 0)          { q0 = s0[0];    q0.y = 0.0f; q1 = s1[0];    q1.y = 0.0f; }
        else if (j < 1024)   { q0 = s0[j];                 q1 = s1[j]; }
        else if (j == 1024)  { q0 = s0[1024]; q0.y = 0.0f; q1 = s1[1024]; q1.y = 0.0f; }
        else { float2 t0 = s0[2048 - j], t1 = s1[2048 - j];
               q0 = make_float2(t0.x, -t0.y); q1 = make_float2(t1.x, -t1.y); }
        A2[LP(j)] = make_float2(q0.x - q1.y, q0.y + q1.x);   // E0 + i*E1
    }
    fft_fused<+1>(A2, 2048, 11, tid, 256);
    const float scl = 1.0f / 2048.0f;
    for (int j = tid; j < 2048; j += 256) {
        float2 v = A2[LP(j)];
        A4[LP(j)]        = make_float2(v.x * scl, 0.0f);
        A4[LP(4095 - j)] = make_float2(v.y * scl, 0.0f);
    }
    fft_fused<-1>(A4, 4096, 12, tid, 256);
    for (int F = tid; F <= 2048; F += 256)
        kfout[(size_t)h * 2049 + F] = A4[LP(F)];
}

// ---------------- K3: transpose x (2048 x 4096) -> u (4096 x 2048) ----------
__global__ void k3_transpose(const float* __restrict__ x, float* __restrict__ u)
{
    __shared__ float tile[32][33];
    int p0 = blockIdx.x * 32;
    int l0 = blockIdx.y * 32;
    int tx = threadIdx.x, ty = threadIdx.y;
    for (int i = ty; i < 32; i += 8)
        tile[i][tx] = x[(size_t)(l0 + i) * 4096 + p0 + tx];
    __syncthreads();
    for (int i = ty; i < 32; i += 8)
        u[(size_t)(p0 + i) * 2048 + l0 + tx] = tile[tx][i];
}

// ---------------- K4: pair-packed conv via register radix-16 FFT ------------
__global__ __launch_bounds__(256) void k4_conv(const float* __restrict__ u,
        const float2* __restrict__ kf, const float* __restrict__ Dp, float* __restrict__ yg)
{
    __shared__ float2 lds[4366];
    int h  = blockIdx.x & 255;
    int bp = blockIdx.x >> 8;
    int t  = threadIdx.x;
    const float* u0 = u + (size_t)((2*bp)   * 256 + h) * 2048;
    const float* u1 = u + (size_t)((2*bp+1) * 256 + h) * 2048;
    float2 v[16], us[8];
    #pragma unroll
    for (int n1 = 0; n1 < 8; ++n1) {
        int j = n1 * 256 + t;
        us[n1] = make_float2(u0[j], u1[j]);
        v[n1] = us[n1];
        v[n1 + 8] = make_float2(0.f, 0.f);
    }
    fft4096p<-1>(v, lds, t);
    const float2* kfh = kf + (size_t)h * 2049;
    #pragma unroll
    for (int j2 = 0; j2 < 16; ++j2) {
        int f = t + 256 * j2;
        float2 K;
        if (f <= 2048) K = kfh[f];
        else { float2 q = kfh[4096 - f]; K = make_float2(q.x, -q.y); }
        v[j2] = cmulf(v[j2], K);
    }
    fft4096p<+1>(v, lds, t);
    float d = Dp[h];
    float* o0 = yg + (size_t)((2*bp)   * 256 + h) * 2048;
    float* o1 = yg + (size_t)((2*bp+1) * 256 + h) * 2048;
    const float iscl = 1.0f / 4096.0f;
    #pragma unroll
    for (int j2 = 0; j2 < 8; ++j2) {
        int l = t + 256 * j2;
        float y0 = v[j2].x * iscl + d * us[j2].x;
        float y1 = v[j2].y * iscl + d * us[j2].y;
        o0[l] = 0.5f * y0 * (1.0f + erff(y0 * 0.70710678118654752f));
        o1[l] = 0.5f * y1 * (1.0f + erff(y1 * 0.70710678118654752f));
    }
}

// ---------------- K56: MFMA GEMM + GLU + residual + LayerNorm + store -------
__global__ __launch_bounds__(256, 2) void k56_gemm_glu_ln(const float* __restrict__ yg,
        const unsigned short* __restrict__ Wb, const float* __restrict__ bout,
        const float* __restrict__ u, const float* __restrict__ gamma,
        const float* __restrict__ beta, float* __restrict__ out)
{
    __shared__ short yt[64][264];
    __shared__ short Wl[64][264];
    __shared__ float bo[512];
    __shared__ float gb2[512];
    int b  = blockIdx.y;
    int l0 = blockIdx.x * 64;
    int tid = threadIdx.x;
    int lane = tid & 63, w = tid >> 6;
    int cc = lane & 15, gg = lane >> 4;
    bo[tid] = bout[tid]; bo[tid + 256] = bout[tid + 256];
    gb2[tid] = gamma[tid]; gb2[tid + 256] = beta[tid];
    int li = tid & 63;
    #pragma unroll 4
    for (int it = 0; it < 64; ++it) {
        int hh = (tid >> 6) + it * 4;
        float vv = yg[(size_t)(b * 256 + hh) * 2048 + l0 + li];
        yt[li][hh] = (short)f2bf(vv);
    }
    __syncthreads();
    const short* brow = &yt[16 * w + cc][0];
    bf16x8 bfr[8];
    #pragma unroll
    for (int ks = 0; ks < 8; ++ks) bfr[ks] = *(const bf16x8*)(brow + ks * 32 + gg * 8);
    f32x4 acc[32];
    #pragma unroll
    for (int tt = 0; tt < 32; ++tt) acc[tt] = (f32x4){0.f, 0.f, 0.f, 0.f};
    const int fr = tid >> 5, fch = tid & 31;
    bf16x8 pre[8];
    #pragma unroll
    for (int j = 0; j < 8; ++j)
        pre[j] = *(const bf16x8*)(Wb + (size_t)(fr + j * 8) * 256 + fch * 8);
    #pragma unroll
    for (int c = 0; c < 8; ++c) {
        #pragma unroll
        for (int j = 0; j < 8; ++j)
            *(bf16x8*)&Wl[fr + j * 8][fch * 8] = pre[j];
        __syncthreads();
        if (c < 7) {
            #pragma unroll
            for (int j = 0; j < 8; ++j)
                pre[j] = *(const bf16x8*)(Wb + (size_t)((c + 1) * 64 + fr + j * 8) * 256 + fch * 8);
        }
        #pragma unroll
        for (int ks = 0; ks < 8; ++ks) {
            #pragma unroll
            for (int tl = 0; tl < 4; ++tl) {
                bf16x8 afrag = *(const bf16x8*)&Wl[tl * 16 + cc][ks * 32 + gg * 8];
                acc[c * 4 + tl] = __builtin_amdgcn_mfma_f32_16x16x32_bf16(
                    afrag, bfr[ks], acc[c * 4 + tl], 0, 0, 0);
            }
        }
        __syncthreads();
    }
    int l = l0 + 16 * w + cc;
    const float* up = u + (size_t)b * 256 * 2048 + l;
    float s = 0.f, q2 = 0.f;
    #pragma unroll
    for (int tt = 0; tt < 16; ++tt) {
        #pragma unroll
        for (int r = 0; r < 4; ++r) {
            int P = tt * 16 + gg * 4 + r;
            float ya = acc[tt][r] + bo[P];
            float gb = acc[tt + 16][r] + bo[256 + P];
            float gv = ya / (1.0f + expf(-gb));
            float val = gv + up[(size_t)P * 2048];
            acc[tt][r] = val;
            s += val; q2 += val * val;
        }
    }
    s  += __shfl_xor(s, 16);  s  += __shfl_xor(s, 32);
    q2 += __shfl_xor(q2, 16); q2 += __shfl_xor(q2, 32);
    float mu = s * (1.0f / 256.0f);
    float var = q2 * (1.0f / 256.0f) - mu * mu;
    float rstd = rsqrtf(var + 1e-5f);
    float* ob = out + (size_t)(l * 16 + b) * 256;
    #pragma unroll
    for (int tt = 0; tt < 16; ++tt) {
        int P0 = tt * 16 + gg * 4;
        float4 o4;
        o4.x = (acc[tt][0] - mu) * rstd * gb2[P0 + 0] + gb2[256 + P0 + 0];
        o4.y = (acc[tt][1] - mu) * rstd * gb2[P0 + 1] + gb2[256 + P0 + 1];
        o4.z = (acc[tt][2] - mu) * rstd * gb2[P0 + 2] + gb2[256 + P0 + 2];
        o4.w = (acc[tt][3] - mu) * rstd * gb2[P0 + 3] + gb2[256 + P0 + 3];
        *(float4*)(ob + P0) = o4;
    }
}

// ---------------- launch ----------------
extern "C" void kernel_launch(void* const* d_in, const int* in_sizes, int n_in,
                              void* d_out, int out_size, void* d_ws, size_t ws_size,
                              hipStream_t stream)
{
    (void)in_sizes; (void)n_in; (void)out_size; (void)ws_size;
    const float* x      = (const float*)d_in[0];
    const float* log_dt = (const float*)d_in[1];
    const float* wlr    = (const float*)d_in[2];
    const float* wim    = (const float*)d_in[3];
    const float* Pre    = (const float*)d_in[4];
    const float* Pim    = (const float*)d_in[5];
    const float* Bre    = (const float*)d_in[6];
    const float* Bim    = (const float*)d_in[7];
    const float* Cre    = (const float*)d_in[8];
    const float* Cim    = (const float*)d_in[9];
    const float* Dp     = (const float*)d_in[10];
    const float* Wout   = (const float*)d_in[11];
    const float* bout   = (const float*)d_in[12];
    const float* gamma  = (const float*)d_in[13];
    const float* beta   = (const float*)d_in[14];

    float* ws  = (float*)d_ws;
    float* u   = ws;                 // 32MB (B,H,L)
    float* yg  = ws + 8388608;       // 32MB (B,H,L)
    char*  ob  = (char*)d_out;
    float2* kF  = (float2*)(ob);                       // 4,198,400 B
    float2* kfo = (float2*)(ob + 4198400);             // 4,196,352 B
    unsigned short* Wb = (unsigned short*)(ob + 8394752);  // 262,144 B

    k0_convW<<<dim3(512), 256, 0, stream>>>(Wout, Wb);
    k1_kergen<<<dim3(256, 5), 256, 0, stream>>>(log_dt, wlr, wim, Pre, Pim, Bre, Bim, Cre, Cim, kF);
    k2_kernelfft<<<dim3(256), 256, 0, stream>>>(kF, kfo);
    k3_transpose<<<dim3(128, 64), dim3(32, 8), 0, stream>>>(x, u);
    k4_conv<<<dim3(2048), 256, 0, stream>>>(u, kfo, Dp, yg);
    k56_gemm_glu_ln<<<dim3(32, 16), 256, 0, stream>>>(yg, Wb, bout, u, gamma, beta, (float*)d_out);
}

// Round 13
// 130.715 us; speedup vs baseline: 3.5070x; 1.0613x over previous
//
#include <hip/hip_runtime.h>

// S4 (SSSD) layer: L=2048, B=16, H=256, N2=32. Output f32.
// R13: k1 inner loop on HW v_rcp_f32 + float4-packed LDS tables (was: precise
// f32 div sequences + 7 scalar ds_reads per pole). yg intermediate now bf16
// (k4 writes rounded bits; k56 staging reads them raw) - same GEMM precision,
// half the L3 round-trip. Rest identical to R12.

#define PI_F 3.14159265358979323846f
#define LP(i) ((i) + ((i) >> 4))    // LDS pad for k2's fft_fused

typedef __attribute__((ext_vector_type(8))) short bf16x8;
typedef __attribute__((ext_vector_type(4))) float f32x4;

__device__ __forceinline__ float2 cmulf(float2 a, float2 b) {
    return make_float2(a.x*b.x - a.y*b.y, a.x*b.y + a.y*b.x);
}
__device__ __forceinline__ unsigned short f2bf(float f) {
    unsigned int u = __float_as_uint(f);
    u += 0x7fffu + ((u >> 16) & 1u);
    return (unsigned short)(u >> 16);
}

// ---------------- 16-pt register FFT, compile-time twiddles -----------------
template<int SGN>
__device__ __forceinline__ void fft16(float2 v[16]) {
    float2 tsw;
#define SW(i,j) { tsw = v[i]; v[i] = v[j]; v[j] = tsw; }
    SW(1,8) SW(2,4) SW(3,12) SW(5,10) SW(7,14) SW(11,13)
#undef SW
    const float C8[8] = {1.f, 0.92387953251f, 0.70710678119f, 0.38268343236f,
                         0.f, -0.38268343236f, -0.70710678119f, -0.92387953251f};
    const float S8[8] = {0.f, 0.38268343236f, 0.70710678119f, 0.92387953251f,
                         1.f, 0.92387953251f, 0.70710678119f, 0.38268343236f};
    #pragma unroll
    for (int s = 0; s < 4; ++s) {
        const int Ns = 1 << s;
        #pragma unroll
        for (int j = 0; j < 8; ++j) {
            const int k  = j & (Ns - 1);
            const int i0 = ((j >> s) << (s + 1)) | k;
            const int i1 = i0 + Ns;
            const int ti = k << (3 - s);
            const float cs = C8[ti];
            const float sn = (SGN < 0) ? -S8[ti] : S8[ti];
            float2 a = v[i0], b = v[i1];
            float2 t = make_float2(cs*b.x - sn*b.y, cs*b.y + sn*b.x);
            v[i0] = make_float2(a.x + t.x, a.y + t.y);
            v[i1] = make_float2(a.x - t.x, a.y - t.y);
        }
    }
}

// ------------- 4096-pt FFT: 3 phases of fft16, 2 LDS transposes -------------
template<int SGN>
__device__ __forceinline__ void fft4096p(float2 v[16], float2* lds, int t) {
    fft16<SGN>(v);
    float s1, c1;
    __sincosf((float)SGN * (2.0f * PI_F / 4096.0f) * (float)t, &s1, &c1);
    float2 w1 = make_float2(c1, s1), cur = make_float2(1.f, 0.f);
    #pragma unroll
    for (int k = 1; k < 16; ++k) { cur = cmulf(cur, w1); v[k] = cmulf(v[k], cur); }
    __syncthreads();
    #pragma unroll
    for (int k = 0; k < 16; ++k) lds[t * 17 + k] = v[k];
    __syncthreads();
    const int k1 = t & 15, m2 = t >> 4;
    #pragma unroll
    for (int m1 = 0; m1 < 16; ++m1) v[m1] = lds[(m1 * 16 + m2) * 17 + k1];
    fft16<SGN>(v);
    float s2, c2;
    __sincosf((float)SGN * (2.0f * PI_F / 256.0f) * (float)m2, &s2, &c2);
    float2 w2 = make_float2(c2, s2); cur = make_float2(1.f, 0.f);
    #pragma unroll
    for (int j = 1; j < 16; ++j) { cur = cmulf(cur, w2); v[j] = cmulf(v[j], cur); }
    __syncthreads();
    #pragma unroll
    for (int j = 0; j < 16; ++j) lds[m2 * 273 + j * 17 + k1] = v[j];
    __syncthreads();
    #pragma unroll
    for (int m = 0; m < 16; ++m) v[m] = lds[m * 273 + (t >> 4) * 17 + k1];
    fft16<SGN>(v);
}

// -------- in-LDS fused double-stage FFT (kept for k2; verified) -------------
template<int SGN>
__device__ __forceinline__ void fft_fused(float2* A, int N, int logN,
                                          int tid, int nthr) {
    __syncthreads();
    for (int j = tid; j < N; j += nthr) {
        int r = (int)(__brev((unsigned)j) >> (32 - logN));
        if (r > j) { float2 t = A[LP(j)]; A[LP(j)] = A[LP(r)]; A[LP(r)] = t; }
    }
    __syncthreads();
    int s = 0;
    if (logN & 1) {
        for (int j = tid; j < (N >> 1); j += nthr) {
            int i0 = 2 * j;
            float2 a = A[LP(i0)], b = A[LP(i0 + 1)];
            A[LP(i0)]     = make_float2(a.x + b.x, a.y + b.y);
            A[LP(i0 + 1)] = make_float2(a.x - b.x, a.y - b.y);
        }
        __syncthreads();
        s = 1;
    }
    for (; s < logN; s += 2) {
        const int Ns = 1 << s;
        for (int g = tid; g < (N >> 2); g += nthr) {
            int k = g & (Ns - 1);
            int base = ((g >> s) << (s + 2)) | k;
            float2 a0 = A[LP(base)];
            float2 a1 = A[LP(base + Ns)];
            float2 a2 = A[LP(base + 2*Ns)];
            float2 a3 = A[LP(base + 3*Ns)];
            float ang1 = (float)SGN * PI_F * (float)k / (float)Ns;
            float sn1, cs1; __sincosf(ang1, &sn1, &cs1);
            float2 t = make_float2(cs1*a1.x - sn1*a1.y, cs1*a1.y + sn1*a1.x);
            float2 b0 = make_float2(a0.x + t.x, a0.y + t.y);
            float2 b1 = make_float2(a0.x - t.x, a0.y - t.y);
            t = make_float2(cs1*a3.x - sn1*a3.y, cs1*a3.y + sn1*a3.x);
            float2 b2 = make_float2(a2.x + t.x, a2.y + t.y);
            float2 b3 = make_float2(a2.x - t.x, a2.y - t.y);
            float ang2 = (float)SGN * PI_F * (float)k / (float)(2 * Ns);
            float sn2, cs2; __sincosf(ang2, &sn2, &cs2);
            t = make_float2(cs2*b2.x - sn2*b2.y, cs2*b2.y + sn2*b2.x);
            A[LP(base)]        = make_float2(b0.x + t.x, b0.y + t.y);
            A[LP(base + 2*Ns)] = make_float2(b0.x - t.x, b0.y - t.y);
            float c2p, s2p;
            if (SGN < 0) { c2p = sn2; s2p = -cs2; } else { c2p = -sn2; s2p = cs2; }
            t = make_float2(c2p*b3.x - s2p*b3.y, c2p*b3.y + s2p*b3.x);
            A[LP(base + Ns)]   = make_float2(b1.x + t.x, b1.y + t.y);
            A[LP(base + 3*Ns)] = make_float2(b1.x - t.x, b1.y - t.y);
        }
        __syncthreads();
    }
}

// ---------------- K0: convert W [512][256] f32 -> bf16 (row-major) ----------
__global__ void k0_convW(const float* __restrict__ W, unsigned short* __restrict__ Wb)
{
    int i = blockIdx.x * 256 + threadIdx.x;
    if (i < 512 * 256) Wb[i] = f2bf(W[i]);
}

// ---------------- K1: NPLR kernel generation (f32, rcp + packed LDS) --------
// grid (256, 5): block = one h, 256 f-values.
__global__ __launch_bounds__(256) void k1_kergen(const float* __restrict__ log_dt,
                          const float* __restrict__ wlr, const float* __restrict__ wim,
                          const float* __restrict__ Pre, const float* __restrict__ Pim,
                          const float* __restrict__ Bre, const float* __restrict__ Bim,
                          const float* __restrict__ Cre, const float* __restrict__ Cim,
                          float2* __restrict__ kf_out)
{
    __shared__ float4 T0[32], T1[32], T2[32], T3[32];
    // T0=(wre,wi,v00.x,v00.y) T1=(v01,v02) T2=(v10,v11) T3=(v12,-,-)
    int h = blockIdx.x;
    int tid = threadIdx.x;
    float dt = expf(log_dt[h]);
    if (tid < 32) {
        int i = h * 32 + tid;
        float wre = -expf(wlr[i]) * dt;
        float wi  = wim[i] * dt;
        float2 B  = make_float2(Bre[i], Bim[i]);
        float2 P  = make_float2(Pre[i], Pim[i]);
        float2 C0 = make_float2(Cre[i], Cim[i]);
        float2 C1 = make_float2(Cre[8192 + i], Cim[8192 + i]);
        float2 Pc = make_float2(P.x, -P.y);
        float2 v00 = cmulf(B, C0), v01 = cmulf(B, C1), v02 = cmulf(B, Pc);
        float2 v10 = cmulf(P, C0), v11 = cmulf(P, C1), v12 = cmulf(P, Pc);
        T0[tid] = make_float4(wre, wi, v00.x, v00.y);
        T1[tid] = make_float4(v01.x, v01.y, v02.x, v02.y);
        T2[tid] = make_float4(v10.x, v10.y, v11.x, v11.y);
        T3[tid] = make_float4(v12.x, v12.y, 0.f, 0.f);
    }
    __syncthreads();
    int f = blockIdx.y * 256 + tid;
    if (f > 1024) return;
    float ang = -(2.0f * PI_F / 2048.0f) * (float)f;
    float sn, cs;
    sincosf(ang, &sn, &cs);
    float2 onep = make_float2(1.0f + cs, sn);
    float invo = __builtin_amdgcn_rcpf(onep.x * onep.x + onep.y * onep.y);
    float2 oinv = make_float2(onep.x * invo, -onep.y * invo);     // 1/onep
    float2 z = cmulf(make_float2(2.0f * (1.0f - cs), -2.0f * sn), oinv);
    float2 r00 = {0,0}, r01 = {0,0}, r02 = {0,0};
    float2 r10 = {0,0}, r11 = {0,0}, r12 = {0,0};
    #pragma unroll 4
    for (int n = 0; n < 32; ++n) {
        float4 a  = T0[n];
        float4 bq = T1[n];
        float4 cq = T2[n];
        float4 dq = T3[n];
        float zx  = z.x - a.x;
        float d1y = z.y - a.y;
        float d2y = z.y + a.y;
        float inv1 = __builtin_amdgcn_rcpf(zx * zx + d1y * d1y);
        float inv2 = __builtin_amdgcn_rcpf(zx * zx + d2y * d2y);
        float sx = zx * (inv1 + inv2);
        float dx = zx * (inv1 - inv2);
        float sy = -(d1y * inv1 + d2y * inv2);
        float dy = d1y * inv1 - d2y * inv2;
        r00.x += a.z*sx + a.w*dy;  r00.y += a.z*sy + a.w*dx;
        r01.x += bq.x*sx + bq.y*dy; r01.y += bq.x*sy + bq.y*dx;
        r02.x += bq.z*sx + bq.w*dy; r02.y += bq.z*sy + bq.w*dx;
        r10.x += cq.x*sx + cq.y*dy; r10.y += cq.x*sy + cq.y*dx;
        r11.x += cq.z*sx + cq.w*dy; r11.y += cq.z*sy + cq.w*dx;
        r12.x += dq.x*sx + dq.y*dy; r12.y += dq.x*sy + dq.y*dx;
    }
    r00.x *= dt; r00.y *= dt; r01.x *= dt; r01.y *= dt; r02.x *= dt; r02.y *= dt;
    r10.x *= dt; r10.y *= dt; r11.x *= dt; r11.y *= dt; r12.x *= dt; r12.y *= dt;
    float2 den = make_float2(1.0f + r12.x, r12.y);
    float invd = __builtin_amdgcn_rcpf(den.x * den.x + den.y * den.y);
    float2 idn = make_float2(den.x * invd, -den.y * invd);
    float2 fac = make_float2(2.0f * oinv.x, 2.0f * oinv.y);
    float2 t0 = cmulf(cmulf(r02, r10), idn);
    float2 k0 = cmulf(make_float2(r00.x - t0.x, r00.y - t0.y), fac);
    float2 t1 = cmulf(cmulf(r02, r11), idn);
    float2 k1 = cmulf(make_float2(r01.x - t1.x, r01.y - t1.y), fac);
    kf_out[(size_t)h * 1025 + f]         = k0;
    kf_out[(size_t)(256 + h) * 1025 + f] = k1;
}

// ---------------- K2: packed irfft(ch0,ch1) -> kk -> fft4096 -> kf ----------
__global__ __launch_bounds__(256) void k2_kernelfft(const float2* __restrict__ kfin,
                                                    float2* __restrict__ kfout)
{
    __shared__ float2 A2[2176];
    __shared__ float2 A4[4352];
    int h = blockIdx.x, tid = threadIdx.x;
    const float2* s0 = kfin + (size_t)h * 1025;
    const float2* s1 = kfin + (size_t)(256 + h) * 1025;
    for (int j = tid; j < 2048; j += 256) {
        float2 q0, q1;
        if (j == 0)          { q0 = s0[0];    q0.y = 0.0f; q1 = s1[0];    q1.y = 0.0f; }
        else if (j < 1024)   { q0 = s0[j];                 q1 = s1[j]; }
        else if (j == 1024)  { q0 = s0[1024]; q0.y = 0.0f; q1 = s1[1024]; q1.y = 0.0f; }
        else { float2 t0 = s0[2048 - j], t1 = s1[2048 - j];
               q0 = make_float2(t0.x, -t0.y); q1 = make_float2(t1.x, -t1.y); }
        A2[LP(j)] = make_float2(q0.x - q1.y, q0.y + q1.x);   // E0 + i*E1
    }
    fft_fused<+1>(A2, 2048, 11, tid, 256);
    const float scl = 1.0f / 2048.0f;
    for (int j = tid; j < 2048; j += 256) {
        float2 v = A2[LP(j)];
        A4[LP(j)]        = make_float2(v.x * scl, 0.0f);
        A4[LP(4095 - j)] = make_float2(v.y * scl, 0.0f);
    }
    fft_fused<-1>(A4, 4096, 12, tid, 256);
    for (int F = tid; F <= 2048; F += 256)
        kfout[(size_t)h * 2049 + F] = A4[LP(F)];
}

// ---------------- K3: transpose x (2048 x 4096) -> u (4096 x 2048) ----------
__global__ void k3_transpose(const float* __restrict__ x, float* __restrict__ u)
{
    __shared__ float tile[32][33];
    int p0 = blockIdx.x * 32;
    int l0 = blockIdx.y * 32;
    int tx = threadIdx.x, ty = threadIdx.y;
    for (int i = ty; i < 32; i += 8)
        tile[i][tx] = x[(size_t)(l0 + i) * 4096 + p0 + tx];
    __syncthreads();
    for (int i = ty; i < 32; i += 8)
        u[(size_t)(p0 + i) * 2048 + l0 + tx] = tile[tx][i];
}

// ---------------- K4: pair-packed conv via register radix-16 FFT ------------
// yg written as bf16 bits (GEMM input precision unchanged - k56 rounded anyway)
__global__ __launch_bounds__(256) void k4_conv(const float* __restrict__ u,
        const float2* __restrict__ kf, const float* __restrict__ Dp,
        unsigned short* __restrict__ ygb)
{
    __shared__ float2 lds[4366];
    int h  = blockIdx.x & 255;
    int bp = blockIdx.x >> 8;
    int t  = threadIdx.x;
    const float* u0 = u + (size_t)((2*bp)   * 256 + h) * 2048;
    const float* u1 = u + (size_t)((2*bp+1) * 256 + h) * 2048;
    float2 v[16], us[8];
    #pragma unroll
    for (int n1 = 0; n1 < 8; ++n1) {
        int j = n1 * 256 + t;
        us[n1] = make_float2(u0[j], u1[j]);
        v[n1] = us[n1];
        v[n1 + 8] = make_float2(0.f, 0.f);
    }
    fft4096p<-1>(v, lds, t);
    const float2* kfh = kf + (size_t)h * 2049;
    #pragma unroll
    for (int j2 = 0; j2 < 16; ++j2) {
        int f = t + 256 * j2;
        float2 K;
        if (f <= 2048) K = kfh[f];
        else { float2 q = kfh[4096 - f]; K = make_float2(q.x, -q.y); }
        v[j2] = cmulf(v[j2], K);
    }
    fft4096p<+1>(v, lds, t);
    float d = Dp[h];
    unsigned short* o0 = ygb + (size_t)((2*bp)   * 256 + h) * 2048;
    unsigned short* o1 = ygb + (size_t)((2*bp+1) * 256 + h) * 2048;
    const float iscl = 1.0f / 4096.0f;
    #pragma unroll
    for (int j2 = 0; j2 < 8; ++j2) {
        int l = t + 256 * j2;
        float y0 = v[j2].x * iscl + d * us[j2].x;
        float y1 = v[j2].y * iscl + d * us[j2].y;
        o0[l] = f2bf(0.5f * y0 * (1.0f + erff(y0 * 0.70710678118654752f)));
        o1[l] = f2bf(0.5f * y1 * (1.0f + erff(y1 * 0.70710678118654752f)));
    }
}

// ---------------- K56: MFMA GEMM + GLU + residual + LayerNorm + store -------
__global__ __launch_bounds__(256, 2) void k56_gemm_glu_ln(const unsigned short* __restrict__ ygb,
        const unsigned short* __restrict__ Wb, const float* __restrict__ bout,
        const float* __restrict__ u, const float* __restrict__ gamma,
        const float* __restrict__ beta, float* __restrict__ out)
{
    __shared__ short yt[64][264];
    __shared__ short Wl[64][264];
    __shared__ float bo[512];
    __shared__ float gb2[512];
    int b  = blockIdx.y;
    int l0 = blockIdx.x * 64;
    int tid = threadIdx.x;
    int lane = tid & 63, w = tid >> 6;
    int cc = lane & 15, gg = lane >> 4;
    bo[tid] = bout[tid]; bo[tid + 256] = bout[tid + 256];
    gb2[tid] = gamma[tid]; gb2[tid + 256] = beta[tid];
    int li = tid & 63;
    #pragma unroll 4
    for (int it = 0; it < 64; ++it) {
        int hh = (tid >> 6) + it * 4;
        yt[li][hh] = (short)ygb[(size_t)(b * 256 + hh) * 2048 + l0 + li];
    }
    __syncthreads();
    const short* brow = &yt[16 * w + cc][0];
    bf16x8 bfr[8];
    #pragma unroll
    for (int ks = 0; ks < 8; ++ks) bfr[ks] = *(const bf16x8*)(brow + ks * 32 + gg * 8);
    f32x4 acc[32];
    #pragma unroll
    for (int tt = 0; tt < 32; ++tt) acc[tt] = (f32x4){0.f, 0.f, 0.f, 0.f};
    const int fr = tid >> 5, fch = tid & 31;
    bf16x8 pre[8];
    #pragma unroll
    for (int j = 0; j < 8; ++j)
        pre[j] = *(const bf16x8*)(Wb + (size_t)(fr + j * 8) * 256 + fch * 8);
    #pragma unroll
    for (int c = 0; c < 8; ++c) {
        #pragma unroll
        for (int j = 0; j < 8; ++j)
            *(bf16x8*)&Wl[fr + j * 8][fch * 8] = pre[j];
        __syncthreads();
        if (c < 7) {
            #pragma unroll
            for (int j = 0; j < 8; ++j)
                pre[j] = *(const bf16x8*)(Wb + (size_t)((c + 1) * 64 + fr + j * 8) * 256 + fch * 8);
        }
        #pragma unroll
        for (int ks = 0; ks < 8; ++ks) {
            #pragma unroll
            for (int tl = 0; tl < 4; ++tl) {
                bf16x8 afrag = *(const bf16x8*)&Wl[tl * 16 + cc][ks * 32 + gg * 8];
                acc[c * 4 + tl] = __builtin_amdgcn_mfma_f32_16x16x32_bf16(
                    afrag, bfr[ks], acc[c * 4 + tl], 0, 0, 0);
            }
        }
        __syncthreads();
    }
    int l = l0 + 16 * w + cc;
    const float* up = u + (size_t)b * 256 * 2048 + l;
    float s = 0.f, q2 = 0.f;
    #pragma unroll
    for (int tt = 0; tt < 16; ++tt) {
        #pragma unroll
        for (int r = 0; r < 4; ++r) {
            int P = tt * 16 + gg * 4 + r;
            float ya = acc[tt][r] + bo[P];
            float gb = acc[tt + 16][r] + bo[256 + P];
            float gv = ya / (1.0f + expf(-gb));
            float val = gv + up[(size_t)P * 2048];
            acc[tt][r] = val;
            s += val; q2 += val * val;
        }
    }
    s  += __shfl_xor(s, 16);  s  += __shfl_xor(s, 32);
    q2 += __shfl_xor(q2, 16); q2 += __shfl_xor(q2, 32);
    float mu = s * (1.0f / 256.0f);
    float var = q2 * (1.0f / 256.0f) - mu * mu;
    float rstd = rsqrtf(var + 1e-5f);
    float* ob = out + (size_t)(l * 16 + b) * 256;
    #pragma unroll
    for (int tt = 0; tt < 16; ++tt) {
        int P0 = tt * 16 + gg * 4;
        float4 o4;
        o4.x = (acc[tt][0] - mu) * rstd * gb2[P0 + 0] + gb2[256 + P0 + 0];
        o4.y = (acc[tt][1] - mu) * rstd * gb2[P0 + 1] + gb2[256 + P0 + 1];
        o4.z = (acc[tt][2] - mu) * rstd * gb2[P0 + 2] + gb2[256 + P0 + 2];
        o4.w = (acc[tt][3] - mu) * rstd * gb2[P0 + 3] + gb2[256 + P0 + 3];
        *(float4*)(ob + P0) = o4;
    }
}

// ---------------- launch ----------------
extern "C" void kernel_launch(void* const* d_in, const int* in_sizes, int n_in,
                              void* d_out, int out_size, void* d_ws, size_t ws_size,
                              hipStream_t stream)
{
    (void)in_sizes; (void)n_in; (void)out_size; (void)ws_size;
    const float* x      = (const float*)d_in[0];
    const float* log_dt = (const float*)d_in[1];
    const float* wlr    = (const float*)d_in[2];
    const float* wim    = (const float*)d_in[3];
    const float* Pre    = (const float*)d_in[4];
    const float* Pim    = (const float*)d_in[5];
    const float* Bre    = (const float*)d_in[6];
    const float* Bim    = (const float*)d_in[7];
    const float* Cre    = (const float*)d_in[8];
    const float* Cim    = (const float*)d_in[9];
    const float* Dp     = (const float*)d_in[10];
    const float* Wout   = (const float*)d_in[11];
    const float* bout   = (const float*)d_in[12];
    const float* gamma  = (const float*)d_in[13];
    const float* beta   = (const float*)d_in[14];

    float* ws  = (float*)d_ws;
    float* u   = ws;                              // 32MB (B,H,L) f32
    unsigned short* ygb = (unsigned short*)(ws + 8388608);   // 16MB (B,H,L) bf16
    char*  ob  = (char*)d_out;
    float2* kF  = (float2*)(ob);                       // 4,198,400 B
    float2* kfo = (float2*)(ob + 4198400);             // 4,196,352 B
    unsigned short* Wb = (unsigned short*)(ob + 8394752);  // 262,144 B

    k0_convW<<<dim3(512), 256, 0, stream>>>(Wout, Wb);
    k1_kergen<<<dim3(256, 5), 256, 0, stream>>>(log_dt, wlr, wim, Pre, Pim, Bre, Bim, Cre, Cim, kF);
    k2_kernelfft<<<dim3(256), 256, 0, stream>>>(kF, kfo);
    k3_transpose<<<dim3(128, 64), dim3(32, 8), 0, stream>>>(x, u);
    k4_conv<<<dim3(2048), 256, 0, stream>>>(u, kfo, Dp, ygb);
    k56_gemm_glu_ln<<<dim3(32, 16), 256, 0, stream>>>(ygb, Wb, bout, u, gamma, beta, (float*)d_out);
}